// Round 2
// baseline (308.802 us; speedup 1.0000x reference)
//
#include <hip/hip_runtime.h>
#include <cstdint>
#include <cstddef>

#define N_TOK  16384
#define NEXP   64
#define KDIM   2048
#define KSPLIT 4
#define CAP    256   // ceil(16384/64 * 1.0) = 256

// ---------------------------------------------------------------------------
// Kernel 0: zero the argmax counters (ws is not re-poisoned between replays)
// ---------------------------------------------------------------------------
__global__ void init_cnt(int* __restrict__ ce_cnt) {
  ce_cnt[threadIdx.x] = 0;
}

// ---------------------------------------------------------------------------
// Kernel 1: fp32 GEMM  part[ks] += x[256-row tile] @ W^T   (K split 4 ways)
//   grid = 64 mtiles * 4 ksplits = 256 blocks (1 per CU), 256 threads,
//   thread tile 8x8, LDS tiles transposed for float4 fragment reads.
// ---------------------------------------------------------------------------
constexpr int BM = 256, BK = 32;

__global__ __launch_bounds__(256) void gemm_part(const float* __restrict__ x,
                                                 const float* __restrict__ W,
                                                 float* __restrict__ part) {
  __shared__ float xs[BK][BM];     // 32 KB
  __shared__ float wsb[BK][NEXP];  // 8 KB
  const int mt  = (int)blockIdx.x >> 2;
  const int ks  = (int)blockIdx.x & 3;
  const int tid = (int)threadIdx.x;
  const int r0  = (tid >> 3) * 8;  // 0..248
  const int c0  = (tid & 7) * 8;   // 0..56
  const int kBeg = ks * (KDIM / KSPLIT);
  const int kEnd = kBeg + (KDIM / KSPLIT);

  float acc[8][8];
#pragma unroll
  for (int i = 0; i < 8; ++i)
#pragma unroll
    for (int j = 0; j < 8; ++j) acc[i][j] = 0.f;

  for (int k0 = kBeg; k0 < kEnd; k0 += BK) {
    // stage x tile (256 rows x 32 k), transposed into xs[k][row]
#pragma unroll
    for (int f = 0; f < 8; ++f) {
      int q   = tid + f * 256;       // 0..2047 float4 index
      int row = q >> 3;              // 0..255
      int kq  = (q & 7) << 2;        // 0,4,..,28
      float4 v = *reinterpret_cast<const float4*>(
          &x[(size_t)(mt * BM + row) * KDIM + k0 + kq]);
      xs[kq + 0][row] = v.x;
      xs[kq + 1][row] = v.y;
      xs[kq + 2][row] = v.z;
      xs[kq + 3][row] = v.w;
    }
    // stage W tile (64 rows x 32 k), transposed into wsb[k][col]
#pragma unroll
    for (int f = 0; f < 2; ++f) {
      int q  = tid + f * 256;        // 0..511
      int c  = q >> 3;               // 0..63
      int kq = (q & 7) << 2;
      float4 v = *reinterpret_cast<const float4*>(
          &W[(size_t)c * KDIM + k0 + kq]);
      wsb[kq + 0][c] = v.x;
      wsb[kq + 1][c] = v.y;
      wsb[kq + 2][c] = v.z;
      wsb[kq + 3][c] = v.w;
    }
    __syncthreads();
#pragma unroll 8
    for (int kk = 0; kk < BK; ++kk) {
      float4 xa = *reinterpret_cast<float4*>(&xs[kk][r0]);
      float4 xb = *reinterpret_cast<float4*>(&xs[kk][r0 + 4]);
      float4 wa = *reinterpret_cast<float4*>(&wsb[kk][c0]);
      float4 wb = *reinterpret_cast<float4*>(&wsb[kk][c0 + 4]);
      float xv[8] = {xa.x, xa.y, xa.z, xa.w, xb.x, xb.y, xb.z, xb.w};
      float wv[8] = {wa.x, wa.y, wa.z, wa.w, wb.x, wb.y, wb.z, wb.w};
#pragma unroll
      for (int i = 0; i < 8; ++i)
#pragma unroll
        for (int j = 0; j < 8; ++j) acc[i][j] = fmaf(xv[i], wv[j], acc[i][j]);
    }
    __syncthreads();
  }

  float* pout = part + (size_t)ks * N_TOK * NEXP;
#pragma unroll
  for (int i = 0; i < 8; ++i) {
    size_t base = (size_t)(mt * BM + r0 + i) * NEXP + c0;
    *reinterpret_cast<float4*>(&pout[base]) =
        make_float4(acc[i][0], acc[i][1], acc[i][2], acc[i][3]);
    *reinterpret_cast<float4*>(&pout[base + 4]) =
        make_float4(acc[i][4], acc[i][5], acc[i][6], acc[i][7]);
  }
}

// ---------------------------------------------------------------------------
// Kernel 2: per-row gating. One 64-lane wave per token row.
//   - sum K-split partials -> logit
//   - softmax
//   - bitonic sort (desc by gate, asc by index on ties)  == jax top_k order
//   - inclusive cumsum; chosen = (cum - g) < 0.5 or rank 0
//   - importance = (64 - rank) + g, scattered to tam[row][expert]
//   - lane0: atomic count for ce (argmax one-hot mean)
// ---------------------------------------------------------------------------
__global__ __launch_bounds__(256) void gate_rows(const float* __restrict__ part,
                                                 float* __restrict__ gates,
                                                 float* __restrict__ tam,
                                                 int* __restrict__ ce_cnt) {
  const int lane = (int)threadIdx.x & 63;
  const int wv   = (int)threadIdx.x >> 6;
  const int row  = (int)blockIdx.x * 4 + wv;
  const size_t base = (size_t)row * NEXP;

  float logit = 0.f;
#pragma unroll
  for (int s = 0; s < KSPLIT; ++s)
    logit += part[(size_t)s * N_TOK * NEXP + base + lane];

  float m = logit;
#pragma unroll
  for (int off = 32; off > 0; off >>= 1) m = fmaxf(m, __shfl_xor(m, off));
  float p = expf(logit - m);
  float s = p;
#pragma unroll
  for (int off = 32; off > 0; off >>= 1) s += __shfl_xor(s, off);
  const float gate = p / s;
  gates[base + lane] = gate;

  // bitonic sort, descending, index-ascending tiebreak
  float g = gate;
  int idx = lane;
#pragma unroll
  for (int k = 2; k <= 64; k <<= 1) {
#pragma unroll
    for (int j = k >> 1; j > 0; j >>= 1) {
      float og = __shfl_xor(g, j);
      int   oi = __shfl_xor(idx, j);
      bool iLower    = (lane & j) == 0;
      bool wantFirst = ((lane & k) == 0) ? iLower : !iLower;
      bool otherFirst = (og > g) || (og == g && oi < idx);
      if (otherFirst == wantFirst) { g = og; idx = oi; }
    }
  }

  // inclusive prefix sum over sorted gates
  float cum = g;
#pragma unroll
  for (int off = 1; off < 64; off <<= 1) {
    float t = __shfl_up(cum, off);
    if (lane >= off) cum += t;
  }
  const bool chosen = (lane == 0) || ((cum - g) < 0.5f);
  const float imp = chosen ? ((float)(NEXP - lane) + g) : 0.f;
  tam[base + idx] = imp;  // idx is a permutation per row: full overwrite
  if (lane == 0) atomicAdd(&ce_cnt[idx], 1);
}

// ---------------------------------------------------------------------------
// Kernel 3: per-expert capacity truncation. One block per expert.
//   - stage tam column in dynamic LDS (64 KB), sum gates column for me
//   - exact 256th-largest via 4x8-bit MSB radix select on float bit patterns
//   - equals kept lowest-token-index-first (matches stable jax top_k)
//   - writes combine_weights column: keep && tam>0 ? gate : 0
// ---------------------------------------------------------------------------
__global__ __launch_bounds__(1024) void expert_select(
    const float* __restrict__ gates, const float* __restrict__ tam,
    float* __restrict__ me_sum, float* __restrict__ comb) {
  extern __shared__ float vcol[];  // N_TOK floats
  __shared__ int   hist[256];
  __shared__ float wsum[16];
  __shared__ int   wcnt[16];
  __shared__ unsigned bc_prefix;
  __shared__ int      bc_k;

  const int e    = (int)blockIdx.x;
  const int tid  = (int)threadIdx.x;
  const int lane = tid & 63;
  const int wid  = tid >> 6;

  float gsum = 0.f;
  for (int i = tid; i < N_TOK; i += 1024) {
    vcol[i] = tam[(size_t)i * NEXP + e];
    gsum += gates[(size_t)i * NEXP + e];
  }
#pragma unroll
  for (int off = 32; off > 0; off >>= 1) gsum += __shfl_xor(gsum, off);
  if (lane == 0) wsum[wid] = gsum;
  __syncthreads();
  if (tid == 0) {
    float t = 0.f;
    for (int w2 = 0; w2 < 16; ++w2) t += wsum[w2];
    me_sum[e] = t;
  }

  // radix select: find v* = 256th largest value (as uint bits) and
  // meq = how many values equal to v* are kept.
  unsigned prefix = 0;
  int krem = CAP;
  for (int round = 0; round < 4; ++round) {
    const int shift = 24 - 8 * round;
    const unsigned maskAbove = (round == 0) ? 0u : (0xFFFFFFFFu << (shift + 8));
    __syncthreads();
    if (tid < 256) hist[tid] = 0;
    __syncthreads();
    for (int i = tid; i < N_TOK; i += 1024) {
      unsigned u = __float_as_uint(vcol[i]);
      if ((u & maskAbove) == prefix)
        atomicAdd(&hist[(u >> shift) & 255], 1);
    }
    __syncthreads();
    if (tid == 0) {
      int acc2 = 0;
      int d = 255;
      for (; d > 0; --d) {
        int c = hist[d];
        if (acc2 + c >= krem) break;
        acc2 += c;
      }
      bc_prefix = prefix | ((unsigned)d << shift);
      bc_k = krem - acc2;
    }
    __syncthreads();
    prefix = bc_prefix;
    krem   = bc_k;
  }
  const unsigned vstar = prefix;
  const int meq = krem;

  // index-ordered scan of equals: keep first meq by token index
  const int per = N_TOK / 1024;  // 16 contiguous tokens per thread
  const int beg = tid * per;
  int cnt = 0;
#pragma unroll
  for (int i = 0; i < per; ++i)
    cnt += (__float_as_uint(vcol[beg + i]) == vstar) ? 1 : 0;
  int inc = cnt;
#pragma unroll
  for (int off = 1; off < 64; off <<= 1) {
    int t = __shfl_up(inc, off);
    if (lane >= off) inc += t;
  }
  if (lane == 63) wcnt[wid] = inc;
  __syncthreads();
  if (tid == 0) {
    int run = 0;
    for (int w2 = 0; w2 < 16; ++w2) { int t = wcnt[w2]; wcnt[w2] = run; run += t; }
  }
  __syncthreads();
  int exc = (inc - cnt) + wcnt[wid];

  for (int i = 0; i < per; ++i) {
    const int t = beg + i;
    const unsigned u = __float_as_uint(vcol[t]);
    bool keep;
    if (u == vstar) { keep = (exc < meq); ++exc; }
    else            { keep = (u > vstar); }
    const float outv = (keep && u != 0u) ? gates[(size_t)t * NEXP + e] : 0.f;
    comb[(size_t)t * NEXP + e] = outv;
  }
}

// ---------------------------------------------------------------------------
// Kernel 4: aux loss  l_aux = sum_e (me_e/N * ce_e/N) * E
// ---------------------------------------------------------------------------
__global__ void aux_loss(const float* __restrict__ me_sum,
                         const int* __restrict__ ce_cnt,
                         float* __restrict__ out0) {
  const int lane = (int)threadIdx.x;
  float v = (me_sum[lane] / (float)N_TOK) *
            ((float)ce_cnt[lane] / (float)N_TOK);
#pragma unroll
  for (int off = 32; off > 0; off >>= 1) v += __shfl_xor(v, off);
  if (lane == 0) out0[0] = v * (float)NEXP;
}

// ---------------------------------------------------------------------------
extern "C" void kernel_launch(void* const* d_in, const int* in_sizes, int n_in,
                              void* d_out, int out_size, void* d_ws, size_t ws_size,
                              hipStream_t stream) {
  const float* x = (const float*)d_in[0];
  const float* W = (const float*)d_in[1];
  float* out = (float*)d_out;
  float* ws  = (float*)d_ws;

  const size_t NE = (size_t)N_TOK * NEXP;
  float* part  = ws;                    // KSPLIT * NE floats (16 MB)
  float* gates = ws + KSPLIT * NE;      // NE floats (4 MB)
  float* tam   = gates + NE;            // NE floats (4 MB)
  float* me    = tam + NE;              // 64 floats
  int*   ce    = (int*)(me + 64);       // 64 ints

  (void)hipFuncSetAttribute((const void*)expert_select,
                            hipFuncAttributeMaxDynamicSharedMemorySize,
                            N_TOK * 4);

  init_cnt<<<1, 64, 0, stream>>>(ce);
  gemm_part<<<(N_TOK / BM) * KSPLIT, 256, 0, stream>>>(x, W, part);
  gate_rows<<<N_TOK / 4, 256, 0, stream>>>(part, gates, tam, ce);
  expert_select<<<NEXP, 1024, N_TOK * 4, stream>>>(gates, tam, me, out + 1);
  aux_loss<<<1, 64, 0, stream>>>(me, ce, out);
}

// Round 3
// 200.436 us; speedup vs baseline: 1.5406x; 1.5406x over previous
//
#include <hip/hip_runtime.h>
#include <cstdint>
#include <cstddef>

#define N_TOK  16384
#define NEXP   64
#define KDIM   2048
#define KSPLIT 4
#define CAP    256   // ceil(16384/64 * 1.0) = 256

// ---------------------------------------------------------------------------
// Kernel 1: fp32 GEMM  part[ks] = x[64-row tile] @ W^T   (K split 4 ways)
//   BM=64: grid = 256 mtiles * 4 ksplits = 1024 blocks (4/CU -> 16 waves/CU),
//   256 threads, thread tile 4x4, LDS tiles transposed for float4 reads.
//   x-fragment reads: 4 distinct addrs/wave (16-lane broadcast) conflict-free;
//   W-fragment reads: 16 addrs, 2-way bank alias = free.
// ---------------------------------------------------------------------------
constexpr int BM = 64, BK = 32;

__global__ __launch_bounds__(256) void gemm_part(const float* __restrict__ x,
                                                 const float* __restrict__ W,
                                                 float* __restrict__ part) {
  __shared__ float xs[BK][BM];     // 8 KB  [k][row]
  __shared__ float wsb[BK][NEXP];  // 8 KB  [k][col]
  const int mt  = (int)blockIdx.x >> 2;
  const int ks  = (int)blockIdx.x & 3;
  const int tid = (int)threadIdx.x;
  const int r0  = (tid >> 4) * 4;  // 0..60
  const int c0  = (tid & 15) * 4;  // 0..60
  const int kBeg = ks * (KDIM / KSPLIT);
  const int kEnd = kBeg + (KDIM / KSPLIT);

  float acc[4][4];
#pragma unroll
  for (int i = 0; i < 4; ++i)
#pragma unroll
    for (int j = 0; j < 4; ++j) acc[i][j] = 0.f;

  for (int k0 = kBeg; k0 < kEnd; k0 += BK) {
    // stage x tile (64 rows x 32 k) transposed: 512 float4, 2 per thread
#pragma unroll
    for (int f = 0; f < 2; ++f) {
      int q   = tid + f * 256;       // 0..511
      int row = q >> 3;              // 0..63
      int kq  = (q & 7) << 2;        // 0,4,..,28
      float4 v = *reinterpret_cast<const float4*>(
          &x[(size_t)(mt * BM + row) * KDIM + k0 + kq]);
      xs[kq + 0][row] = v.x;
      xs[kq + 1][row] = v.y;
      xs[kq + 2][row] = v.z;
      xs[kq + 3][row] = v.w;
    }
    // stage W tile (64 cols x 32 k) transposed: 512 float4, 2 per thread
#pragma unroll
    for (int f = 0; f < 2; ++f) {
      int q  = tid + f * 256;
      int c  = q >> 3;
      int kq = (q & 7) << 2;
      float4 v = *reinterpret_cast<const float4*>(
          &W[(size_t)c * KDIM + k0 + kq]);
      wsb[kq + 0][c] = v.x;
      wsb[kq + 1][c] = v.y;
      wsb[kq + 2][c] = v.z;
      wsb[kq + 3][c] = v.w;
    }
    __syncthreads();
#pragma unroll
    for (int kk = 0; kk < BK; ++kk) {
      float4 xa = *reinterpret_cast<float4*>(&xs[kk][r0]);
      float4 wa = *reinterpret_cast<float4*>(&wsb[kk][c0]);
      float xv[4] = {xa.x, xa.y, xa.z, xa.w};
      float wv[4] = {wa.x, wa.y, wa.z, wa.w};
#pragma unroll
      for (int i = 0; i < 4; ++i)
#pragma unroll
        for (int j = 0; j < 4; ++j) acc[i][j] = fmaf(xv[i], wv[j], acc[i][j]);
    }
    __syncthreads();
  }

  float* pout = part + (size_t)ks * N_TOK * NEXP;
#pragma unroll
  for (int i = 0; i < 4; ++i) {
    size_t base = (size_t)(mt * BM + r0 + i) * NEXP + c0;
    *reinterpret_cast<float4*>(&pout[base]) =
        make_float4(acc[i][0], acc[i][1], acc[i][2], acc[i][3]);
  }
}

// ---------------------------------------------------------------------------
// Kernel 2: per-row gating. One 64-lane wave per token row.
//   - sum K-split partials -> logit; softmax
//   - bitonic sort (desc, index-asc ties) == jax top_k order
//   - cumsum threshold; importance = (64 - rank) + g scattered to tam
//   (argmax counting moved to expert_select: top-1 importance > 64 exactly)
// ---------------------------------------------------------------------------
__global__ __launch_bounds__(256) void gate_rows(const float* __restrict__ part,
                                                 float* __restrict__ gates,
                                                 float* __restrict__ tam) {
  const int lane = (int)threadIdx.x & 63;
  const int wv   = (int)threadIdx.x >> 6;
  const int row  = (int)blockIdx.x * 4 + wv;
  const size_t base = (size_t)row * NEXP;

  float logit = 0.f;
#pragma unroll
  for (int s = 0; s < KSPLIT; ++s)
    logit += part[(size_t)s * N_TOK * NEXP + base + lane];

  float m = logit;
#pragma unroll
  for (int off = 32; off > 0; off >>= 1) m = fmaxf(m, __shfl_xor(m, off));
  float p = expf(logit - m);
  float s = p;
#pragma unroll
  for (int off = 32; off > 0; off >>= 1) s += __shfl_xor(s, off);
  const float gate = p / s;
  gates[base + lane] = gate;

  // bitonic sort, descending, index-ascending tiebreak
  float g = gate;
  int idx = lane;
#pragma unroll
  for (int k = 2; k <= 64; k <<= 1) {
#pragma unroll
    for (int j = k >> 1; j > 0; j >>= 1) {
      float og = __shfl_xor(g, j);
      int   oi = __shfl_xor(idx, j);
      bool iLower    = (lane & j) == 0;
      bool wantFirst = ((lane & k) == 0) ? iLower : !iLower;
      bool otherFirst = (og > g) || (og == g && oi < idx);
      if (otherFirst == wantFirst) { g = og; idx = oi; }
    }
  }

  // inclusive prefix sum over sorted gates
  float cum = g;
#pragma unroll
  for (int off = 1; off < 64; off <<= 1) {
    float t = __shfl_up(cum, off);
    if (lane >= off) cum += t;
  }
  const bool chosen = (lane == 0) || ((cum - g) < 0.5f);
  const float imp = chosen ? ((float)(NEXP - lane) + g) : 0.f;
  tam[base + idx] = imp;  // idx is a permutation per row: full overwrite
}

// ---------------------------------------------------------------------------
// Kernel 3: per-expert capacity truncation. One block per expert.
//   - stage tam column in dynamic LDS (64 KB); sum gates column (me);
//     count argmax hits (ce) as tam > 64.0f (top-1 imp = 64+g, others < 64)
//   - exact 256th-largest via 4x8-bit MSB radix select on float bit patterns
//   - equals kept lowest-token-index-first (matches stable jax top_k)
//   - writes combine_weights column: keep && tam>0 ? gate : 0
// ---------------------------------------------------------------------------
__global__ __launch_bounds__(1024) void expert_select(
    const float* __restrict__ gates, const float* __restrict__ tam,
    float* __restrict__ me_sum, int* __restrict__ ce_cnt,
    float* __restrict__ comb) {
  extern __shared__ float vcol[];  // N_TOK floats
  __shared__ int   hist[256];
  __shared__ float wsum[16];
  __shared__ int   wice[16];
  __shared__ int   wcnt[16];
  __shared__ unsigned bc_prefix;
  __shared__ int      bc_k;

  const int e    = (int)blockIdx.x;
  const int tid  = (int)threadIdx.x;
  const int lane = tid & 63;
  const int wid  = tid >> 6;

  float gsum = 0.f;
  int   ccnt = 0;
  for (int i = tid; i < N_TOK; i += 1024) {
    float v = tam[(size_t)i * NEXP + e];
    vcol[i] = v;
    gsum += gates[(size_t)i * NEXP + e];
    ccnt += (v > 64.0f) ? 1 : 0;
  }
#pragma unroll
  for (int off = 32; off > 0; off >>= 1) {
    gsum += __shfl_xor(gsum, off);
    ccnt += __shfl_xor(ccnt, off);
  }
  if (lane == 0) { wsum[wid] = gsum; wice[wid] = ccnt; }
  __syncthreads();
  if (tid == 0) {
    float t = 0.f;
    int   c = 0;
    for (int w2 = 0; w2 < 16; ++w2) { t += wsum[w2]; c += wice[w2]; }
    me_sum[e] = t;
    ce_cnt[e] = c;
  }

  // radix select: find v* = 256th largest value (as uint bits) and
  // meq = how many values equal to v* are kept.
  unsigned prefix = 0;
  int krem = CAP;
  for (int round = 0; round < 4; ++round) {
    const int shift = 24 - 8 * round;
    const unsigned maskAbove = (round == 0) ? 0u : (0xFFFFFFFFu << (shift + 8));
    __syncthreads();
    if (tid < 256) hist[tid] = 0;
    __syncthreads();
    for (int i = tid; i < N_TOK; i += 1024) {
      unsigned u = __float_as_uint(vcol[i]);
      if ((u & maskAbove) == prefix)
        atomicAdd(&hist[(u >> shift) & 255], 1);
    }
    __syncthreads();
    if (tid == 0) {
      int acc2 = 0;
      int d = 255;
      for (; d > 0; --d) {
        int c = hist[d];
        if (acc2 + c >= krem) break;
        acc2 += c;
      }
      bc_prefix = prefix | ((unsigned)d << shift);
      bc_k = krem - acc2;
    }
    __syncthreads();
    prefix = bc_prefix;
    krem   = bc_k;
  }
  const unsigned vstar = prefix;
  const int meq = krem;

  // index-ordered scan of equals: keep first meq by token index
  const int per = N_TOK / 1024;  // 16 contiguous tokens per thread
  const int beg = tid * per;
  int cnt = 0;
#pragma unroll
  for (int i = 0; i < per; ++i)
    cnt += (__float_as_uint(vcol[beg + i]) == vstar) ? 1 : 0;
  int inc = cnt;
#pragma unroll
  for (int off = 1; off < 64; off <<= 1) {
    int t = __shfl_up(inc, off);
    if (lane >= off) inc += t;
  }
  if (lane == 63) wcnt[wid] = inc;
  __syncthreads();
  if (tid == 0) {
    int run = 0;
    for (int w2 = 0; w2 < 16; ++w2) { int t = wcnt[w2]; wcnt[w2] = run; run += t; }
  }
  __syncthreads();
  int exc = (inc - cnt) + wcnt[wid];

  for (int i = 0; i < per; ++i) {
    const int t = beg + i;
    const unsigned u = __float_as_uint(vcol[t]);
    bool keep;
    if (u == vstar) { keep = (exc < meq); ++exc; }
    else            { keep = (u > vstar); }
    const float outv = (keep && u != 0u) ? gates[(size_t)t * NEXP + e] : 0.f;
    comb[(size_t)t * NEXP + e] = outv;
  }
}

// ---------------------------------------------------------------------------
// Kernel 4: aux loss  l_aux = sum_e (me_e/N * ce_e/N) * E
// ---------------------------------------------------------------------------
__global__ void aux_loss(const float* __restrict__ me_sum,
                         const int* __restrict__ ce_cnt,
                         float* __restrict__ out0) {
  const int lane = (int)threadIdx.x;
  float v = (me_sum[lane] / (float)N_TOK) *
            ((float)ce_cnt[lane] / (float)N_TOK);
#pragma unroll
  for (int off = 32; off > 0; off >>= 1) v += __shfl_xor(v, off);
  if (lane == 0) out0[0] = v * (float)NEXP;
}

// ---------------------------------------------------------------------------
extern "C" void kernel_launch(void* const* d_in, const int* in_sizes, int n_in,
                              void* d_out, int out_size, void* d_ws, size_t ws_size,
                              hipStream_t stream) {
  const float* x = (const float*)d_in[0];
  const float* W = (const float*)d_in[1];
  float* out = (float*)d_out;
  float* ws  = (float*)d_ws;

  const size_t NE = (size_t)N_TOK * NEXP;
  float* part  = ws;                    // KSPLIT * NE floats (16 MB)
  float* gates = ws + KSPLIT * NE;      // NE floats (4 MB)
  float* tam   = gates + NE;            // NE floats (4 MB)
  float* me    = tam + NE;              // 64 floats
  int*   ce    = (int*)(me + 64);       // 64 ints

  (void)hipFuncSetAttribute((const void*)expert_select,
                            hipFuncAttributeMaxDynamicSharedMemorySize,
                            N_TOK * 4);

  gemm_part<<<(N_TOK / BM) * KSPLIT, 256, 0, stream>>>(x, W, part);
  gate_rows<<<N_TOK / 4, 256, 0, stream>>>(part, gates, tam);
  expert_select<<<NEXP, 1024, N_TOK * 4, stream>>>(gates, tam, me, ce, out + 1);
  aux_loss<<<1, 64, 0, stream>>>(me, ce, out);
}

// Round 4
// 112.359 us; speedup vs baseline: 2.7483x; 1.7839x over previous
//
#include <hip/hip_runtime.h>
#include <cstdint>
#include <cstddef>

#define N_TOK  16384
#define NEXP   64
#define KDIM   2048
#define KSPLIT 4
#define CAP    256   // ceil(16384/64 * 1.0) = 256
#define NE_TOT ((size_t)N_TOK * NEXP)

// ---------------------------------------------------------------------------
// Kernel 1: fp32 GEMM  part[ks] = x[64-row tile] @ W^T   (K split 4 ways)
//   unchanged from R2 (occupancy 4 blocks/CU, 16 waves/CU).
// ---------------------------------------------------------------------------
constexpr int BM = 64, BK = 32;

__global__ __launch_bounds__(256) void gemm_part(const float* __restrict__ x,
                                                 const float* __restrict__ W,
                                                 float* __restrict__ part) {
  __shared__ float xs[BK][BM];     // 8 KB  [k][row]
  __shared__ float wsb[BK][NEXP];  // 8 KB  [k][col]
  const int mt  = (int)blockIdx.x >> 2;
  const int ks  = (int)blockIdx.x & 3;
  const int tid = (int)threadIdx.x;
  const int r0  = (tid >> 4) * 4;
  const int c0  = (tid & 15) * 4;
  const int kBeg = ks * (KDIM / KSPLIT);
  const int kEnd = kBeg + (KDIM / KSPLIT);

  float acc[4][4];
#pragma unroll
  for (int i = 0; i < 4; ++i)
#pragma unroll
    for (int j = 0; j < 4; ++j) acc[i][j] = 0.f;

  for (int k0 = kBeg; k0 < kEnd; k0 += BK) {
#pragma unroll
    for (int f = 0; f < 2; ++f) {
      int q   = tid + f * 256;
      int row = q >> 3;
      int kq  = (q & 7) << 2;
      float4 v = *reinterpret_cast<const float4*>(
          &x[(size_t)(mt * BM + row) * KDIM + k0 + kq]);
      xs[kq + 0][row] = v.x;
      xs[kq + 1][row] = v.y;
      xs[kq + 2][row] = v.z;
      xs[kq + 3][row] = v.w;
    }
#pragma unroll
    for (int f = 0; f < 2; ++f) {
      int q  = tid + f * 256;
      int c  = q >> 3;
      int kq = (q & 7) << 2;
      float4 v = *reinterpret_cast<const float4*>(
          &W[(size_t)c * KDIM + k0 + kq]);
      wsb[kq + 0][c] = v.x;
      wsb[kq + 1][c] = v.y;
      wsb[kq + 2][c] = v.z;
      wsb[kq + 3][c] = v.w;
    }
    __syncthreads();
#pragma unroll
    for (int kk = 0; kk < BK; ++kk) {
      float4 xa = *reinterpret_cast<float4*>(&xs[kk][r0]);
      float4 wa = *reinterpret_cast<float4*>(&wsb[kk][c0]);
      float xv[4] = {xa.x, xa.y, xa.z, xa.w};
      float wv[4] = {wa.x, wa.y, wa.z, wa.w};
#pragma unroll
      for (int i = 0; i < 4; ++i)
#pragma unroll
        for (int j = 0; j < 4; ++j) acc[i][j] = fmaf(xv[i], wv[j], acc[i][j]);
    }
    __syncthreads();
  }

  float* pout = part + (size_t)ks * NE_TOT;
#pragma unroll
  for (int i = 0; i < 4; ++i) {
    size_t base = (size_t)(mt * BM + r0 + i) * NEXP + c0;
    *reinterpret_cast<float4*>(&pout[base]) =
        make_float4(acc[i][0], acc[i][1], acc[i][2], acc[i][3]);
  }
}

// ---------------------------------------------------------------------------
// Kernel 2: per-row gating -> TRANSPOSED outputs gatesT[e][t], tamT[e][t].
//   1024 threads = 16 waves; each wave does 4 rows (unrolled for shuffle-
//   latency hiding); 64x65 LDS tiles; transposed writeout is coalesced
//   256B segments per expert.
// ---------------------------------------------------------------------------
__global__ __launch_bounds__(1024) void gate_rows(const float* __restrict__ part,
                                                  float* __restrict__ gatesT,
                                                  float* __restrict__ tamT) {
  __shared__ float gt[64][65];
  __shared__ float tt[64][65];
  const int tid  = (int)threadIdx.x;
  const int lane = tid & 63;
  const int wid  = tid >> 6;
  const int row0 = (int)blockIdx.x * 64;

#pragma unroll
  for (int r = 0; r < 4; ++r) {
    const int rloc = wid * 4 + r;
    const size_t base = (size_t)(row0 + rloc) * NEXP;

    float logit = 0.f;
#pragma unroll
    for (int s = 0; s < KSPLIT; ++s)
      logit += part[(size_t)s * NE_TOT + base + lane];

    float m = logit;
#pragma unroll
    for (int off = 32; off > 0; off >>= 1) m = fmaxf(m, __shfl_xor(m, off));
    float p = expf(logit - m);
    float sum = p;
#pragma unroll
    for (int off = 32; off > 0; off >>= 1) sum += __shfl_xor(sum, off);
    const float gate = p / sum;

    // bitonic sort, descending, index-ascending tiebreak (== jax top_k)
    float g = gate;
    int idx = lane;
#pragma unroll
    for (int k = 2; k <= 64; k <<= 1) {
#pragma unroll
      for (int j = k >> 1; j > 0; j >>= 1) {
        float og = __shfl_xor(g, j);
        int   oi = __shfl_xor(idx, j);
        bool iLower     = (lane & j) == 0;
        bool wantFirst  = ((lane & k) == 0) ? iLower : !iLower;
        bool otherFirst = (og > g) || (og == g && oi < idx);
        if (otherFirst == wantFirst) { g = og; idx = oi; }
      }
    }

    // inclusive prefix sum over sorted gates
    float cum = g;
#pragma unroll
    for (int off = 1; off < 64; off <<= 1) {
      float t = __shfl_up(cum, off);
      if (lane >= off) cum += t;
    }
    const bool chosen = (lane == 0) || ((cum - g) < 0.5f);
    const float imp = chosen ? ((float)(NEXP - lane) + g) : 0.f;

    gt[rloc][lane] = gate;
    tt[rloc][idx]  = imp;   // idx is a permutation: full row fill, 2-way banks
  }
  __syncthreads();

#pragma unroll
  for (int p = 0; p < 4; ++p) {
    const int e = p * 16 + wid;
    gatesT[(size_t)e * N_TOK + row0 + lane] = gt[lane][e];
    tamT  [(size_t)e * N_TOK + row0 + lane] = tt[lane][e];
  }
}

// ---------------------------------------------------------------------------
// Kernel 3: per-expert capacity truncation on TRANSPOSED columns.
//   All global access coalesced (contiguous 64KB per expert, L2-resident).
//   Radix select: zero-skip + per-wave privatized histograms + wave-parallel
//   suffix-scan for the crossing bin. nnz<=CAP fast path.
//   Writes combT[e][t] (transposed; aliased onto dead `part` buffer).
// ---------------------------------------------------------------------------
__global__ __launch_bounds__(1024) void expert_select(
    const float* __restrict__ gatesT, const float* __restrict__ tamT,
    float* __restrict__ me_sum, int* __restrict__ ce_cnt,
    float* __restrict__ combT) {
  __shared__ int   hist16[16][256];   // per-wave privatized
  __shared__ int   hist[256];
  __shared__ float wsum[16];
  __shared__ int   wice[16];
  __shared__ int   wnnz[16];
  __shared__ int   wcnt[16];
  __shared__ unsigned sh_prefix;
  __shared__ int      sh_k;
  __shared__ int      sh_nnz;

  const int e    = (int)blockIdx.x;
  const int tid  = (int)threadIdx.x;
  const int lane = tid & 63;
  const int wid  = tid >> 6;
  const float* tcol = tamT   + (size_t)e * N_TOK;
  const float* gcol = gatesT + (size_t)e * N_TOK;

  // pass 1: me (gate sum), ce (count imp>64: exactly the argmax hits),
  //         nnz (nonzero importances)
  float gsum = 0.f;
  int ccnt = 0, nnzl = 0;
#pragma unroll
  for (int k = 0; k < 4; ++k) {
    int i4 = tid + k * 1024;
    float4 tv = reinterpret_cast<const float4*>(tcol)[i4];
    float4 gv = reinterpret_cast<const float4*>(gcol)[i4];
    gsum += gv.x + gv.y + gv.z + gv.w;
    ccnt += (tv.x > 64.f) + (tv.y > 64.f) + (tv.z > 64.f) + (tv.w > 64.f);
    nnzl += (tv.x != 0.f) + (tv.y != 0.f) + (tv.z != 0.f) + (tv.w != 0.f);
  }
#pragma unroll
  for (int off = 32; off > 0; off >>= 1) {
    gsum += __shfl_xor(gsum, off);
    ccnt += __shfl_xor(ccnt, off);
    nnzl += __shfl_xor(nnzl, off);
  }
  if (lane == 0) { wsum[wid] = gsum; wice[wid] = ccnt; wnnz[wid] = nnzl; }
  __syncthreads();
  if (tid == 0) {
    float t = 0.f; int c = 0, nz = 0;
    for (int w = 0; w < 16; ++w) { t += wsum[w]; c += wice[w]; nz += wnnz[w]; }
    me_sum[e] = t; ce_cnt[e] = c; sh_nnz = nz;
  }
  __syncthreads();
  const int nnz = sh_nnz;

  unsigned vstar = 0u;
  int meq = 0;
  if (nnz > CAP) {
    unsigned prefix = 0;
    int krem = CAP;
    for (int round = 0; round < 4; ++round) {
      const int shift = 24 - 8 * round;
      const unsigned maskAbove =
          (round == 0) ? 0u : (0xFFFFFFFFu << (shift + 8));
      for (int z = tid; z < 16 * 256; z += 1024) ((int*)hist16)[z] = 0;
      __syncthreads();
#pragma unroll
      for (int k = 0; k < 16; ++k) {
        unsigned u = __float_as_uint(tcol[tid + k * 1024]);
        if (u != 0u && (u & maskAbove) == prefix)
          atomicAdd(&hist16[wid][(u >> shift) & 255], 1);
      }
      __syncthreads();
      if (tid < 256) {
        int s = 0;
#pragma unroll
        for (int w = 0; w < 16; ++w) s += hist16[w][tid];
        hist[tid] = s;
      }
      __syncthreads();
      if (wid == 0) {
        // lane owns bins lane*4 .. lane*4+3; wave-parallel suffix scan
        int h0 = hist[lane * 4 + 0], h1 = hist[lane * 4 + 1];
        int h2 = hist[lane * 4 + 2], h3 = hist[lane * 4 + 3];
        int lsum = h0 + h1 + h2 + h3;
        int suf = lsum;
#pragma unroll
        for (int off = 1; off < 64; off <<= 1) {
          int t = __shfl_down(suf, off);
          if (lane + off < 64) suf += t;
        }
        int above = suf - lsum;            // sum over lanes > lane
        int S3 = above + h3, S2 = S3 + h2, S1 = S2 + h1, S0 = S1 + h0;
        // crossing: largest d with suffix(d) >= krem
        if (S0 >= krem && S1    < krem) { sh_prefix = prefix | ((unsigned)(lane*4+0) << shift); sh_k = krem - S1;    }
        if (S1 >= krem && S2    < krem) { sh_prefix = prefix | ((unsigned)(lane*4+1) << shift); sh_k = krem - S2;    }
        if (S2 >= krem && S3    < krem) { sh_prefix = prefix | ((unsigned)(lane*4+2) << shift); sh_k = krem - S3;    }
        if (S3 >= krem && above < krem) { sh_prefix = prefix | ((unsigned)(lane*4+3) << shift); sh_k = krem - above; }
      }
      __syncthreads();
      prefix = sh_prefix;
      krem   = sh_k;
      __syncthreads();
    }
    vstar = prefix;
    meq   = krem;
  }

  // index-ordered equals scan: keep first meq equal-valued by token index
  const int beg = tid * 16;
  float4 tq[4];
#pragma unroll
  for (int q = 0; q < 4; ++q)
    tq[q] = reinterpret_cast<const float4*>(tcol)[tid * 4 + q];
  int cnt = 0;
#pragma unroll
  for (int q = 0; q < 4; ++q) {
    cnt += (__float_as_uint(tq[q].x) == vstar);
    cnt += (__float_as_uint(tq[q].y) == vstar);
    cnt += (__float_as_uint(tq[q].z) == vstar);
    cnt += (__float_as_uint(tq[q].w) == vstar);
  }
  int inc = cnt;
#pragma unroll
  for (int off = 1; off < 64; off <<= 1) {
    int t = __shfl_up(inc, off);
    if (lane >= off) inc += t;
  }
  if (lane == 63) wcnt[wid] = inc;
  __syncthreads();
  if (tid == 0) {
    int run = 0;
    for (int w = 0; w < 16; ++w) { int t = wcnt[w]; wcnt[w] = run; run += t; }
  }
  __syncthreads();
  int exc = (inc - cnt) + wcnt[wid];

  float* ccol = combT + (size_t)e * N_TOK;
#pragma unroll
  for (int q = 0; q < 4; ++q) {
    float4 gq = reinterpret_cast<const float4*>(gcol)[tid * 4 + q];
    float ov[4];
    const float tv[4] = {tq[q].x, tq[q].y, tq[q].z, tq[q].w};
    const float gv[4] = {gq.x, gq.y, gq.z, gq.w};
#pragma unroll
    for (int j = 0; j < 4; ++j) {
      unsigned u = __float_as_uint(tv[j]);
      bool keep;
      if (u == vstar) { keep = (exc < meq); ++exc; }
      else            { keep = (u > vstar); }
      ov[j] = (keep && u != 0u) ? gv[j] : 0.f;
    }
    reinterpret_cast<float4*>(ccol)[tid * 4 + q] =
        make_float4(ov[0], ov[1], ov[2], ov[3]);
  }
}

// ---------------------------------------------------------------------------
// Kernel 4: transpose combT[e][t] -> out[t][e]  (both sides coalesced)
// ---------------------------------------------------------------------------
__global__ __launch_bounds__(1024) void transpose_out(
    const float* __restrict__ combT, float* __restrict__ out1) {
  __shared__ float tile[64][65];
  const int tid  = (int)threadIdx.x;
  const int lane = tid & 63;
  const int wid  = tid >> 6;
  const int tok0 = (int)blockIdx.x * 64;
#pragma unroll
  for (int p = 0; p < 4; ++p) {
    const int e = p * 16 + wid;
    tile[lane][e] = combT[(size_t)e * N_TOK + tok0 + lane];
  }
  __syncthreads();
#pragma unroll
  for (int q = 0; q < 4; ++q) {
    const int tok = q * 16 + wid;
    out1[(size_t)(tok0 + tok) * NEXP + lane] = tile[tok][lane];
  }
}

// ---------------------------------------------------------------------------
// Kernel 5: aux loss  l_aux = sum_e (me_e/N * ce_e/N) * E
// ---------------------------------------------------------------------------
__global__ void aux_loss(const float* __restrict__ me_sum,
                         const int* __restrict__ ce_cnt,
                         float* __restrict__ out0) {
  const int lane = (int)threadIdx.x;
  float v = (me_sum[lane] / (float)N_TOK) *
            ((float)ce_cnt[lane] / (float)N_TOK);
#pragma unroll
  for (int off = 32; off > 0; off >>= 1) v += __shfl_xor(v, off);
  if (lane == 0) out0[0] = v * (float)NEXP;
}

// ---------------------------------------------------------------------------
extern "C" void kernel_launch(void* const* d_in, const int* in_sizes, int n_in,
                              void* d_out, int out_size, void* d_ws, size_t ws_size,
                              hipStream_t stream) {
  const float* x = (const float*)d_in[0];
  const float* W = (const float*)d_in[1];
  float* out = (float*)d_out;
  float* ws  = (float*)d_ws;

  float* part   = ws;                   // KSPLIT * NE_TOT floats (16 MB)
  float* combT  = ws;                   // aliases part: part is dead by then
  float* gatesT = ws + KSPLIT * NE_TOT; // NE_TOT floats (4 MB)
  float* tamT   = gatesT + NE_TOT;      // NE_TOT floats (4 MB)
  float* me     = tamT + NE_TOT;        // 64 floats
  int*   ce     = (int*)(me + 64);      // 64 ints

  gemm_part<<<(N_TOK / BM) * KSPLIT, 256, 0, stream>>>(x, W, part);
  gate_rows<<<N_TOK / 64, 1024, 0, stream>>>(part, gatesT, tamT);
  expert_select<<<NEXP, 1024, 0, stream>>>(gatesT, tamT, me, ce, combT);
  transpose_out<<<N_TOK / 64, 1024, 0, stream>>>(combT, out + 1);
  aux_loss<<<1, 64, 0, stream>>>(me, ce, out);
}

// Round 5
// 104.718 us; speedup vs baseline: 2.9489x; 1.0730x over previous
//
#include <hip/hip_runtime.h>
#include <cstdint>
#include <cstddef>

#define N_TOK  16384
#define NEXP   64
#define KDIM   2048
#define CAP    256   // ceil(16384/64 * 1.0) = 256
#define NE_TOT ((size_t)N_TOK * NEXP)

// ---------------------------------------------------------------------------
// Kernel 1: fp32 GEMM  part[ks] = x[128-row tile] @ W^T   (K split KS ways)
//   BM=128, 256 threads, per-thread tile 8x4 -> per kk: 32 FMA vs 3 ds_read
//   (VALU-bound 1.8:1). LDS tiles k-transposed WITH XOR swizzle
//   col' = col ^ (((k>>2)&7)<<2): staging writes 2-way (free) instead of
//   8-way conflicts; fragment reads stay 16B-aligned (swizzle bits 2-4 only,
//   4-groups permute among themselves). KS=8 -> grid 1024 = 4 blocks/CU,
//   24 KB LDS -> 16 waves/CU.
// ---------------------------------------------------------------------------
constexpr int BM = 128, BK = 32;

template <int KS>
__global__ __launch_bounds__(256) void gemm_part(const float* __restrict__ x,
                                                 const float* __restrict__ W,
                                                 float* __restrict__ part) {
  __shared__ float xs[BK][BM];     // 16 KB  [k][row^swz]
  __shared__ float wsb[BK][NEXP];  //  8 KB  [k][col^swz]
  const int mt  = (int)blockIdx.x / KS;
  const int ks  = (int)blockIdx.x % KS;
  const int tid = (int)threadIdx.x;
  const int r0  = (tid >> 4) * 8;  // 0..120
  const int c0  = (tid & 15) * 4;  // 0..60
  const int kBeg = ks * (KDIM / KS);
  const int kEnd = kBeg + (KDIM / KS);

  float acc[8][4];
#pragma unroll
  for (int i = 0; i < 8; ++i)
#pragma unroll
    for (int j = 0; j < 4; ++j) acc[i][j] = 0.f;

  for (int k0 = kBeg; k0 < kEnd; k0 += BK) {
    // stage x tile (128 rows x 32 k): 1024 float4, 4 per thread
#pragma unroll
    for (int f = 0; f < 4; ++f) {
      int q   = tid + f * 256;       // 0..1023
      int row = q >> 3;              // 0..127
      int kq  = (q & 7) << 2;        // 0,4,..,28
      float4 v = *reinterpret_cast<const float4*>(
          &x[(size_t)(mt * BM + row) * KDIM + k0 + kq]);
      int rr = row ^ kq;             // swz = ((kq>>2)&7)<<2 == kq (kq<32, mult of 4)
      xs[kq + 0][rr] = v.x;
      xs[kq + 1][rr] = v.y;
      xs[kq + 2][rr] = v.z;
      xs[kq + 3][rr] = v.w;
    }
    // stage W tile (64 cols x 32 k): 512 float4, 2 per thread
#pragma unroll
    for (int f = 0; f < 2; ++f) {
      int q  = tid + f * 256;        // 0..511
      int c  = q >> 3;               // 0..63
      int kq = (q & 7) << 2;
      float4 v = *reinterpret_cast<const float4*>(
          &W[(size_t)c * KDIM + k0 + kq]);
      int cc = c ^ kq;
      wsb[kq + 0][cc] = v.x;
      wsb[kq + 1][cc] = v.y;
      wsb[kq + 2][cc] = v.z;
      wsb[kq + 3][cc] = v.w;
    }
    __syncthreads();
#pragma unroll 8
    for (int kk = 0; kk < BK; ++kk) {
      const int s = kk & 28;         // ((kk>>2)&7)<<2
      float4 xa = *reinterpret_cast<float4*>(&xs[kk][(r0)     ^ s]);
      float4 xb = *reinterpret_cast<float4*>(&xs[kk][(r0 + 4) ^ s]);
      float4 wa = *reinterpret_cast<float4*>(&wsb[kk][c0 ^ s]);
      float xv[8] = {xa.x, xa.y, xa.z, xa.w, xb.x, xb.y, xb.z, xb.w};
      float wv[4] = {wa.x, wa.y, wa.z, wa.w};
#pragma unroll
      for (int i = 0; i < 8; ++i)
#pragma unroll
        for (int j = 0; j < 4; ++j) acc[i][j] = fmaf(xv[i], wv[j], acc[i][j]);
    }
    __syncthreads();
  }

  float* pout = part + (size_t)ks * NE_TOT;
#pragma unroll
  for (int i = 0; i < 8; ++i) {
    size_t base = (size_t)(mt * BM + r0 + i) * NEXP + c0;
    *reinterpret_cast<float4*>(&pout[base]) =
        make_float4(acc[i][0], acc[i][1], acc[i][2], acc[i][3]);
  }
}

// ---------------------------------------------------------------------------
// Kernel 2: per-row gating -> TRANSPOSED outputs gatesT[e][t], tamT[e][t].
// ---------------------------------------------------------------------------
template <int KS>
__global__ __launch_bounds__(1024) void gate_rows(const float* __restrict__ part,
                                                  float* __restrict__ gatesT,
                                                  float* __restrict__ tamT) {
  __shared__ float gt[64][65];
  __shared__ float tt[64][65];
  const int tid  = (int)threadIdx.x;
  const int lane = tid & 63;
  const int wid  = tid >> 6;
  const int row0 = (int)blockIdx.x * 64;

#pragma unroll
  for (int r = 0; r < 4; ++r) {
    const int rloc = wid * 4 + r;
    const size_t base = (size_t)(row0 + rloc) * NEXP;

    float logit = 0.f;
#pragma unroll
    for (int s = 0; s < KS; ++s)
      logit += part[(size_t)s * NE_TOT + base + lane];

    float m = logit;
#pragma unroll
    for (int off = 32; off > 0; off >>= 1) m = fmaxf(m, __shfl_xor(m, off));
    float p = expf(logit - m);
    float sum = p;
#pragma unroll
    for (int off = 32; off > 0; off >>= 1) sum += __shfl_xor(sum, off);
    const float gate = p / sum;

    // bitonic sort, descending, index-ascending tiebreak (== jax top_k)
    float g = gate;
    int idx = lane;
#pragma unroll
    for (int k = 2; k <= 64; k <<= 1) {
#pragma unroll
      for (int j = k >> 1; j > 0; j >>= 1) {
        float og = __shfl_xor(g, j);
        int   oi = __shfl_xor(idx, j);
        bool iLower     = (lane & j) == 0;
        bool wantFirst  = ((lane & k) == 0) ? iLower : !iLower;
        bool otherFirst = (og > g) || (og == g && oi < idx);
        if (otherFirst == wantFirst) { g = og; idx = oi; }
      }
    }

    // inclusive prefix sum over sorted gates
    float cum = g;
#pragma unroll
    for (int off = 1; off < 64; off <<= 1) {
      float t = __shfl_up(cum, off);
      if (lane >= off) cum += t;
    }
    const bool chosen = (lane == 0) || ((cum - g) < 0.5f);
    const float imp = chosen ? ((float)(NEXP - lane) + g) : 0.f;

    gt[rloc][lane] = gate;
    tt[rloc][idx]  = imp;   // idx is a permutation: full row fill
  }
  __syncthreads();

#pragma unroll
  for (int p = 0; p < 4; ++p) {
    const int e = p * 16 + wid;
    gatesT[(size_t)e * N_TOK + row0 + lane] = gt[lane][e];
    tamT  [(size_t)e * N_TOK + row0 + lane] = tt[lane][e];
  }
}

// ---------------------------------------------------------------------------
// Kernel 3: per-expert capacity truncation on TRANSPOSED columns.
//   (unchanged from R4 — verified absmax 0.0, ~10 us)
// ---------------------------------------------------------------------------
__global__ __launch_bounds__(1024) void expert_select(
    const float* __restrict__ gatesT, const float* __restrict__ tamT,
    float* __restrict__ me_sum, int* __restrict__ ce_cnt,
    float* __restrict__ combT) {
  __shared__ int   hist16[16][256];
  __shared__ int   hist[256];
  __shared__ float wsum[16];
  __shared__ int   wice[16];
  __shared__ int   wnnz[16];
  __shared__ int   wcnt[16];
  __shared__ unsigned sh_prefix;
  __shared__ int      sh_k;
  __shared__ int      sh_nnz;

  const int e    = (int)blockIdx.x;
  const int tid  = (int)threadIdx.x;
  const int lane = tid & 63;
  const int wid  = tid >> 6;
  const float* tcol = tamT   + (size_t)e * N_TOK;
  const float* gcol = gatesT + (size_t)e * N_TOK;

  float gsum = 0.f;
  int ccnt = 0, nnzl = 0;
#pragma unroll
  for (int k = 0; k < 4; ++k) {
    int i4 = tid + k * 1024;
    float4 tv = reinterpret_cast<const float4*>(tcol)[i4];
    float4 gv = reinterpret_cast<const float4*>(gcol)[i4];
    gsum += gv.x + gv.y + gv.z + gv.w;
    ccnt += (tv.x > 64.f) + (tv.y > 64.f) + (tv.z > 64.f) + (tv.w > 64.f);
    nnzl += (tv.x != 0.f) + (tv.y != 0.f) + (tv.z != 0.f) + (tv.w != 0.f);
  }
#pragma unroll
  for (int off = 32; off > 0; off >>= 1) {
    gsum += __shfl_xor(gsum, off);
    ccnt += __shfl_xor(ccnt, off);
    nnzl += __shfl_xor(nnzl, off);
  }
  if (lane == 0) { wsum[wid] = gsum; wice[wid] = ccnt; wnnz[wid] = nnzl; }
  __syncthreads();
  if (tid == 0) {
    float t = 0.f; int c = 0, nz = 0;
    for (int w = 0; w < 16; ++w) { t += wsum[w]; c += wice[w]; nz += wnnz[w]; }
    me_sum[e] = t; ce_cnt[e] = c; sh_nnz = nz;
  }
  __syncthreads();
  const int nnz = sh_nnz;

  unsigned vstar = 0u;
  int meq = 0;
  if (nnz > CAP) {
    unsigned prefix = 0;
    int krem = CAP;
    for (int round = 0; round < 4; ++round) {
      const int shift = 24 - 8 * round;
      const unsigned maskAbove =
          (round == 0) ? 0u : (0xFFFFFFFFu << (shift + 8));
      for (int z = tid; z < 16 * 256; z += 1024) ((int*)hist16)[z] = 0;
      __syncthreads();
#pragma unroll
      for (int k = 0; k < 16; ++k) {
        unsigned u = __float_as_uint(tcol[tid + k * 1024]);
        if (u != 0u && (u & maskAbove) == prefix)
          atomicAdd(&hist16[wid][(u >> shift) & 255], 1);
      }
      __syncthreads();
      if (tid < 256) {
        int s = 0;
#pragma unroll
        for (int w = 0; w < 16; ++w) s += hist16[w][tid];
        hist[tid] = s;
      }
      __syncthreads();
      if (wid == 0) {
        int h0 = hist[lane * 4 + 0], h1 = hist[lane * 4 + 1];
        int h2 = hist[lane * 4 + 2], h3 = hist[lane * 4 + 3];
        int lsum = h0 + h1 + h2 + h3;
        int suf = lsum;
#pragma unroll
        for (int off = 1; off < 64; off <<= 1) {
          int t = __shfl_down(suf, off);
          if (lane + off < 64) suf += t;
        }
        int above = suf - lsum;
        int S3 = above + h3, S2 = S3 + h2, S1 = S2 + h1, S0 = S1 + h0;
        if (S0 >= krem && S1    < krem) { sh_prefix = prefix | ((unsigned)(lane*4+0) << shift); sh_k = krem - S1;    }
        if (S1 >= krem && S2    < krem) { sh_prefix = prefix | ((unsigned)(lane*4+1) << shift); sh_k = krem - S2;    }
        if (S2 >= krem && S3    < krem) { sh_prefix = prefix | ((unsigned)(lane*4+2) << shift); sh_k = krem - S3;    }
        if (S3 >= krem && above < krem) { sh_prefix = prefix | ((unsigned)(lane*4+3) << shift); sh_k = krem - above; }
      }
      __syncthreads();
      prefix = sh_prefix;
      krem   = sh_k;
      __syncthreads();
    }
    vstar = prefix;
    meq   = krem;
  }

  float4 tq[4];
#pragma unroll
  for (int q = 0; q < 4; ++q)
    tq[q] = reinterpret_cast<const float4*>(tcol)[tid * 4 + q];
  int cnt = 0;
#pragma unroll
  for (int q = 0; q < 4; ++q) {
    cnt += (__float_as_uint(tq[q].x) == vstar);
    cnt += (__float_as_uint(tq[q].y) == vstar);
    cnt += (__float_as_uint(tq[q].z) == vstar);
    cnt += (__float_as_uint(tq[q].w) == vstar);
  }
  int inc = cnt;
#pragma unroll
  for (int off = 1; off < 64; off <<= 1) {
    int t = __shfl_up(inc, off);
    if (lane >= off) inc += t;
  }
  if (lane == 63) wcnt[wid] = inc;
  __syncthreads();
  if (tid == 0) {
    int run = 0;
    for (int w = 0; w < 16; ++w) { int t = wcnt[w]; wcnt[w] = run; run += t; }
  }
  __syncthreads();
  int exc = (inc - cnt) + wcnt[wid];

  float* ccol = combT + (size_t)e * N_TOK;
#pragma unroll
  for (int q = 0; q < 4; ++q) {
    float4 gq = reinterpret_cast<const float4*>(gcol)[tid * 4 + q];
    float ov[4];
    const float tv[4] = {tq[q].x, tq[q].y, tq[q].z, tq[q].w};
    const float gv[4] = {gq.x, gq.y, gq.z, gq.w};
#pragma unroll
    for (int j = 0; j < 4; ++j) {
      unsigned u = __float_as_uint(tv[j]);
      bool keep;
      if (u == vstar) { keep = (exc < meq); ++exc; }
      else            { keep = (u > vstar); }
      ov[j] = (keep && u != 0u) ? gv[j] : 0.f;
    }
    reinterpret_cast<float4*>(ccol)[tid * 4 + q] =
        make_float4(ov[0], ov[1], ov[2], ov[3]);
  }
}

// ---------------------------------------------------------------------------
// Kernel 4: transpose combT[e][t] -> out[t][e]
// ---------------------------------------------------------------------------
__global__ __launch_bounds__(1024) void transpose_out(
    const float* __restrict__ combT, float* __restrict__ out1) {
  __shared__ float tile[64][65];
  const int tid  = (int)threadIdx.x;
  const int lane = tid & 63;
  const int wid  = tid >> 6;
  const int tok0 = (int)blockIdx.x * 64;
#pragma unroll
  for (int p = 0; p < 4; ++p) {
    const int e = p * 16 + wid;
    tile[lane][e] = combT[(size_t)e * N_TOK + tok0 + lane];
  }
  __syncthreads();
#pragma unroll
  for (int q = 0; q < 4; ++q) {
    const int tok = q * 16 + wid;
    out1[(size_t)(tok0 + tok) * NEXP + lane] = tile[tok][lane];
  }
}

// ---------------------------------------------------------------------------
// Kernel 5: aux loss  l_aux = sum_e (me_e/N * ce_e/N) * E
// ---------------------------------------------------------------------------
__global__ void aux_loss(const float* __restrict__ me_sum,
                         const int* __restrict__ ce_cnt,
                         float* __restrict__ out0) {
  const int lane = (int)threadIdx.x;
  float v = (me_sum[lane] / (float)N_TOK) *
            ((float)ce_cnt[lane] / (float)N_TOK);
#pragma unroll
  for (int off = 32; off > 0; off >>= 1) v += __shfl_xor(v, off);
  if (lane == 0) out0[0] = v * (float)NEXP;
}

// ---------------------------------------------------------------------------
extern "C" void kernel_launch(void* const* d_in, const int* in_sizes, int n_in,
                              void* d_out, int out_size, void* d_ws, size_t ws_size,
                              hipStream_t stream) {
  const float* x = (const float*)d_in[0];
  const float* W = (const float*)d_in[1];
  float* out = (float*)d_out;
  float* ws  = (float*)d_ws;

  // KS=8 needs (8+2)*4MB scratch; fall back to KS=4 if ws is smaller.
  const bool ks8 = ws_size >= (size_t)(8 + 2) * NE_TOT * 4 + 1024;
  const int  KS  = ks8 ? 8 : 4;

  float* part   = ws;                     // KS * 4 MB
  float* combT  = ws;                     // aliases part (dead by then)
  float* gatesT = ws + (size_t)KS * NE_TOT;
  float* tamT   = gatesT + NE_TOT;
  float* me     = tamT + NE_TOT;
  int*   ce     = (int*)(me + 64);

  if (ks8) gemm_part<8><<<(N_TOK / BM) * 8, 256, 0, stream>>>(x, W, part);
  else     gemm_part<4><<<(N_TOK / BM) * 4, 256, 0, stream>>>(x, W, part);
  if (ks8) gate_rows<8><<<N_TOK / 64, 1024, 0, stream>>>(part, gatesT, tamT);
  else     gate_rows<4><<<N_TOK / 64, 1024, 0, stream>>>(part, gatesT, tamT);
  expert_select<<<NEXP, 1024, 0, stream>>>(gatesT, tamT, me, ce, combT);
  transpose_out<<<N_TOK / 64, 1024, 0, stream>>>(combT, out + 1);
  aux_loss<<<1, 64, 0, stream>>>(me, ce, out);
}

// Round 6
// 82.065 us; speedup vs baseline: 3.7629x; 1.2760x over previous
//
#include <hip/hip_runtime.h>
#include <cstdint>
#include <cstddef>

#define N_TOK  16384
#define NEXP   64
#define KDIM   2048
#define CAP    256   // ceil(16384/64 * 1.0) = 256
#define NE_TOT ((size_t)N_TOK * NEXP)

typedef __attribute__((ext_vector_type(8))) short short8;
typedef __attribute__((ext_vector_type(4))) float f32x4;

__device__ __forceinline__ unsigned short bf16_rtn(float f) {
  unsigned u = __float_as_uint(f);
  u += 0x7FFFu + ((u >> 16) & 1u);
  return (unsigned short)(u >> 16);
}
__device__ __forceinline__ float bf16_f(unsigned short h) {
  return __uint_as_float((unsigned)h << 16);
}
__device__ __forceinline__ f32x4 MF(short8 a, short8 b, f32x4 c) {
  return __builtin_amdgcn_mfma_f32_16x16x32_bf16(a, b, c, 0, 0, 0);
}

// ---------------------------------------------------------------------------
// Kernel 0: split W into 3 bf16 digits, packed [k/8][col][8] so a B-fragment
// (8 consecutive k of one col) is one aligned 16-B load, and lanes 0..15
// (cols 0..15) read 256 B contiguous.
// ---------------------------------------------------------------------------
__global__ __launch_bounds__(256) void wdigits(const float* __restrict__ W,
    unsigned short* __restrict__ Wh, unsigned short* __restrict__ Wl,
    unsigned short* __restrict__ Wq) {
  const int e = (int)blockIdx.x * 256 + (int)threadIdx.x;  // 0..131071
  const int col = e >> 11;
  const int k   = e & 2047;
  const float w = W[(size_t)col * KDIM + k];
  const unsigned short h = bf16_rtn(w);
  const float r1 = w - bf16_f(h);
  const unsigned short lo = bf16_rtn(r1);
  const float r2 = r1 - bf16_f(lo);
  const unsigned short q = bf16_rtn(r2);
  const size_t idx = (size_t)(k >> 3) * 512 + (size_t)col * 8 + (k & 7);
  Wh[idx] = h; Wl[idx] = lo; Wq[idx] = q;
}

// ---------------------------------------------------------------------------
// Kernel 1: logits via 6-term split-bf16 MFMA (fp32-grade accuracy).
//   Wave = 32 rows x 64 cols, K split KS ways. No LDS: A from global
//   (2 float4/lane, full 128-B lines), B digits from L2 (coalesced b128).
//   A layout: lane l holds A[row=l&15][k=(l>>4)*8+j]; B: B[k=(l>>4)*8+j][col=l&15];
//   D: row=(l>>4)*4+reg, col=l&15  (m89/m101-verified mappings).
// ---------------------------------------------------------------------------
__device__ __forceinline__ void cvt8(float4 a, float4 b,
                                     short8& h, short8& lo, short8& q) {
  float f[8] = {a.x, a.y, a.z, a.w, b.x, b.y, b.z, b.w};
#pragma unroll
  for (int j = 0; j < 8; ++j) {
    unsigned short hh = bf16_rtn(f[j]);
    float r1 = f[j] - bf16_f(hh);
    unsigned short ll = bf16_rtn(r1);
    float r2 = r1 - bf16_f(ll);
    h[j] = (short)hh; lo[j] = (short)ll; q[j] = (short)bf16_rtn(r2);
  }
}

template <int KS>
__global__ __launch_bounds__(256) void gemm_mfma(const float* __restrict__ x,
    const unsigned short* __restrict__ Wh, const unsigned short* __restrict__ Wl,
    const unsigned short* __restrict__ Wq, float* __restrict__ part) {
  constexpr int NSTEP = (KDIM / KS) / 32;
  const int tid = (int)threadIdx.x;
  const int l   = tid & 63;
  const int wv  = tid >> 6;
  const int gw  = (int)blockIdx.x * 4 + wv;
  const int mt  = gw / KS;            // 512 m-tiles of 32 rows
  const int ks  = gw % KS;
  const int row0 = mt * 32;
  const int kBeg = ks * (KDIM / KS);
  const int lr = l & 15;
  const int lk = l >> 4;

  f32x4 acc00 = {0.f,0.f,0.f,0.f}, acc01 = {0.f,0.f,0.f,0.f};
  f32x4 acc02 = {0.f,0.f,0.f,0.f}, acc03 = {0.f,0.f,0.f,0.f};
  f32x4 acc10 = {0.f,0.f,0.f,0.f}, acc11 = {0.f,0.f,0.f,0.f};
  f32x4 acc12 = {0.f,0.f,0.f,0.f}, acc13 = {0.f,0.f,0.f,0.f};

  const float* pa0 = x + (size_t)(row0 + lr) * KDIM + kBeg + lk * 8;
  const float* pa1 = pa0 + (size_t)16 * KDIM;
  const size_t bbase = ((size_t)((kBeg >> 3) + lk)) * 64 + lr;
  const short8* BH = (const short8*)Wh + bbase;
  const short8* BL = (const short8*)Wl + bbase;
  const short8* BQ = (const short8*)Wq + bbase;

  float4 A0a = *(const float4*)pa0;
  float4 A0b = *(const float4*)(pa0 + 4);
  float4 A1a = *(const float4*)pa1;
  float4 A1b = *(const float4*)(pa1 + 4);

  for (int s = 0; s < NSTEP; ++s) {
    const int so = s * 256;  // 4 k-blocks * 64 frags per step
    // B digit fragments for this step (L2-hot, coalesced)
    short8 b_h0 = BH[so +  0], b_h1 = BH[so + 16], b_h2 = BH[so + 32], b_h3 = BH[so + 48];
    short8 b_l0 = BL[so +  0], b_l1 = BL[so + 16], b_l2 = BL[so + 32], b_l3 = BL[so + 48];
    short8 b_q0 = BQ[so +  0], b_q1 = BQ[so + 16], b_q2 = BQ[so + 32], b_q3 = BQ[so + 48];
    // prefetch next A while converting/computing
    float4 N0a = A0a, N0b = A0b, N1a = A1a, N1b = A1b;
    if (s + 1 < NSTEP) {
      pa0 += 32; pa1 += 32;
      N0a = *(const float4*)pa0;
      N0b = *(const float4*)(pa0 + 4);
      N1a = *(const float4*)pa1;
      N1b = *(const float4*)(pa1 + 4);
    }
    // convert current A to 3 bf16 digits
    short8 a_h0, a_l0, a_q0, a_h1, a_l1, a_q1;
    cvt8(A0a, A0b, a_h0, a_l0, a_q0);
    cvt8(A1a, A1b, a_h1, a_l1, a_q1);

#define CT_BLOCK(ACC0, ACC1, BH_, BL_, BQ_)                          \
    ACC0 = MF(a_h0, BH_, ACC0); ACC0 = MF(a_h0, BL_, ACC0);          \
    ACC0 = MF(a_l0, BH_, ACC0); ACC0 = MF(a_l0, BL_, ACC0);          \
    ACC0 = MF(a_q0, BH_, ACC0); ACC0 = MF(a_h0, BQ_, ACC0);          \
    ACC1 = MF(a_h1, BH_, ACC1); ACC1 = MF(a_h1, BL_, ACC1);          \
    ACC1 = MF(a_l1, BH_, ACC1); ACC1 = MF(a_l1, BL_, ACC1);          \
    ACC1 = MF(a_q1, BH_, ACC1); ACC1 = MF(a_h1, BQ_, ACC1);

    CT_BLOCK(acc00, acc10, b_h0, b_l0, b_q0)
    CT_BLOCK(acc01, acc11, b_h1, b_l1, b_q1)
    CT_BLOCK(acc02, acc12, b_h2, b_l2, b_q2)
    CT_BLOCK(acc03, acc13, b_h3, b_l3, b_q3)
#undef CT_BLOCK

    A0a = N0a; A0b = N0b; A1a = N1a; A1b = N1b;
  }

  float* pout = part + (size_t)ks * NE_TOT;
  const int rb = row0 + lk * 4;
#pragma unroll
  for (int r = 0; r < 4; ++r) {
    pout[(size_t)(rb + r) * 64 +  0 + lr] = acc00[r];
    pout[(size_t)(rb + r) * 64 + 16 + lr] = acc01[r];
    pout[(size_t)(rb + r) * 64 + 32 + lr] = acc02[r];
    pout[(size_t)(rb + r) * 64 + 48 + lr] = acc03[r];
    pout[(size_t)(rb + 16 + r) * 64 +  0 + lr] = acc10[r];
    pout[(size_t)(rb + 16 + r) * 64 + 16 + lr] = acc11[r];
    pout[(size_t)(rb + 16 + r) * 64 + 32 + lr] = acc12[r];
    pout[(size_t)(rb + 16 + r) * 64 + 48 + lr] = acc13[r];
  }
}

// ---------------------------------------------------------------------------
// Kernel 2: per-row gating -> TRANSPOSED outputs gatesT[e][t], tamT[e][t].
//   (unchanged from R5 — verified)
// ---------------------------------------------------------------------------
template <int KS>
__global__ __launch_bounds__(1024) void gate_rows(const float* __restrict__ part,
                                                  float* __restrict__ gatesT,
                                                  float* __restrict__ tamT) {
  __shared__ float gt[64][65];
  __shared__ float tt[64][65];
  const int tid  = (int)threadIdx.x;
  const int lane = tid & 63;
  const int wid  = tid >> 6;
  const int row0 = (int)blockIdx.x * 64;

#pragma unroll
  for (int r = 0; r < 4; ++r) {
    const int rloc = wid * 4 + r;
    const size_t base = (size_t)(row0 + rloc) * NEXP;

    float logit = 0.f;
#pragma unroll
    for (int s = 0; s < KS; ++s)
      logit += part[(size_t)s * NE_TOT + base + lane];

    float m = logit;
#pragma unroll
    for (int off = 32; off > 0; off >>= 1) m = fmaxf(m, __shfl_xor(m, off));
    float p = expf(logit - m);
    float sum = p;
#pragma unroll
    for (int off = 32; off > 0; off >>= 1) sum += __shfl_xor(sum, off);
    const float gate = p / sum;

    float g = gate;
    int idx = lane;
#pragma unroll
    for (int k = 2; k <= 64; k <<= 1) {
#pragma unroll
      for (int j = k >> 1; j > 0; j >>= 1) {
        float og = __shfl_xor(g, j);
        int   oi = __shfl_xor(idx, j);
        bool iLower     = (lane & j) == 0;
        bool wantFirst  = ((lane & k) == 0) ? iLower : !iLower;
        bool otherFirst = (og > g) || (og == g && oi < idx);
        if (otherFirst == wantFirst) { g = og; idx = oi; }
      }
    }

    float cum = g;
#pragma unroll
    for (int off = 1; off < 64; off <<= 1) {
      float t = __shfl_up(cum, off);
      if (lane >= off) cum += t;
    }
    const bool chosen = (lane == 0) || ((cum - g) < 0.5f);
    const float imp = chosen ? ((float)(NEXP - lane) + g) : 0.f;

    gt[rloc][lane] = gate;
    tt[rloc][idx]  = imp;
  }
  __syncthreads();

#pragma unroll
  for (int p = 0; p < 4; ++p) {
    const int e = p * 16 + wid;
    gatesT[(size_t)e * N_TOK + row0 + lane] = gt[lane][e];
    tamT  [(size_t)e * N_TOK + row0 + lane] = tt[lane][e];
  }
}

// ---------------------------------------------------------------------------
// Kernel 3: per-expert capacity truncation (unchanged from R5 — verified)
// ---------------------------------------------------------------------------
__global__ __launch_bounds__(1024) void expert_select(
    const float* __restrict__ gatesT, const float* __restrict__ tamT,
    float* __restrict__ me_sum, int* __restrict__ ce_cnt,
    float* __restrict__ combT) {
  __shared__ int   hist16[16][256];
  __shared__ int   hist[256];
  __shared__ float wsum[16];
  __shared__ int   wice[16];
  __shared__ int   wnnz[16];
  __shared__ int   wcnt[16];
  __shared__ unsigned sh_prefix;
  __shared__ int      sh_k;
  __shared__ int      sh_nnz;

  const int e    = (int)blockIdx.x;
  const int tid  = (int)threadIdx.x;
  const int lane = tid & 63;
  const int wid  = tid >> 6;
  const float* tcol = tamT   + (size_t)e * N_TOK;
  const float* gcol = gatesT + (size_t)e * N_TOK;

  float gsum = 0.f;
  int ccnt = 0, nnzl = 0;
#pragma unroll
  for (int k = 0; k < 4; ++k) {
    int i4 = tid + k * 1024;
    float4 tv = reinterpret_cast<const float4*>(tcol)[i4];
    float4 gv = reinterpret_cast<const float4*>(gcol)[i4];
    gsum += gv.x + gv.y + gv.z + gv.w;
    ccnt += (tv.x > 64.f) + (tv.y > 64.f) + (tv.z > 64.f) + (tv.w > 64.f);
    nnzl += (tv.x != 0.f) + (tv.y != 0.f) + (tv.z != 0.f) + (tv.w != 0.f);
  }
#pragma unroll
  for (int off = 32; off > 0; off >>= 1) {
    gsum += __shfl_xor(gsum, off);
    ccnt += __shfl_xor(ccnt, off);
    nnzl += __shfl_xor(nnzl, off);
  }
  if (lane == 0) { wsum[wid] = gsum; wice[wid] = ccnt; wnnz[wid] = nnzl; }
  __syncthreads();
  if (tid == 0) {
    float t = 0.f; int c = 0, nz = 0;
    for (int w = 0; w < 16; ++w) { t += wsum[w]; c += wice[w]; nz += wnnz[w]; }
    me_sum[e] = t; ce_cnt[e] = c; sh_nnz = nz;
  }
  __syncthreads();
  const int nnz = sh_nnz;

  unsigned vstar = 0u;
  int meq = 0;
  if (nnz > CAP) {
    unsigned prefix = 0;
    int krem = CAP;
    for (int round = 0; round < 4; ++round) {
      const int shift = 24 - 8 * round;
      const unsigned maskAbove =
          (round == 0) ? 0u : (0xFFFFFFFFu << (shift + 8));
      for (int z = tid; z < 16 * 256; z += 1024) ((int*)hist16)[z] = 0;
      __syncthreads();
#pragma unroll
      for (int k = 0; k < 16; ++k) {
        unsigned u = __float_as_uint(tcol[tid + k * 1024]);
        if (u != 0u && (u & maskAbove) == prefix)
          atomicAdd(&hist16[wid][(u >> shift) & 255], 1);
      }
      __syncthreads();
      if (tid < 256) {
        int s = 0;
#pragma unroll
        for (int w = 0; w < 16; ++w) s += hist16[w][tid];
        hist[tid] = s;
      }
      __syncthreads();
      if (wid == 0) {
        int h0 = hist[lane * 4 + 0], h1 = hist[lane * 4 + 1];
        int h2 = hist[lane * 4 + 2], h3 = hist[lane * 4 + 3];
        int lsum = h0 + h1 + h2 + h3;
        int suf = lsum;
#pragma unroll
        for (int off = 1; off < 64; off <<= 1) {
          int t = __shfl_down(suf, off);
          if (lane + off < 64) suf += t;
        }
        int above = suf - lsum;
        int S3 = above + h3, S2 = S3 + h2, S1 = S2 + h1, S0 = S1 + h0;
        if (S0 >= krem && S1    < krem) { sh_prefix = prefix | ((unsigned)(lane*4+0) << shift); sh_k = krem - S1;    }
        if (S1 >= krem && S2    < krem) { sh_prefix = prefix | ((unsigned)(lane*4+1) << shift); sh_k = krem - S2;    }
        if (S2 >= krem && S3    < krem) { sh_prefix = prefix | ((unsigned)(lane*4+2) << shift); sh_k = krem - S3;    }
        if (S3 >= krem && above < krem) { sh_prefix = prefix | ((unsigned)(lane*4+3) << shift); sh_k = krem - above; }
      }
      __syncthreads();
      prefix = sh_prefix;
      krem   = sh_k;
      __syncthreads();
    }
    vstar = prefix;
    meq   = krem;
  }

  float4 tq[4];
#pragma unroll
  for (int q = 0; q < 4; ++q)
    tq[q] = reinterpret_cast<const float4*>(tcol)[tid * 4 + q];
  int cnt = 0;
#pragma unroll
  for (int q = 0; q < 4; ++q) {
    cnt += (__float_as_uint(tq[q].x) == vstar);
    cnt += (__float_as_uint(tq[q].y) == vstar);
    cnt += (__float_as_uint(tq[q].z) == vstar);
    cnt += (__float_as_uint(tq[q].w) == vstar);
  }
  int inc = cnt;
#pragma unroll
  for (int off = 1; off < 64; off <<= 1) {
    int t = __shfl_up(inc, off);
    if (lane >= off) inc += t;
  }
  if (lane == 63) wcnt[wid] = inc;
  __syncthreads();
  if (tid == 0) {
    int run = 0;
    for (int w = 0; w < 16; ++w) { int t = wcnt[w]; wcnt[w] = run; run += t; }
  }
  __syncthreads();
  int exc = (inc - cnt) + wcnt[wid];

  float* ccol = combT + (size_t)e * N_TOK;
#pragma unroll
  for (int q = 0; q < 4; ++q) {
    float4 gq = reinterpret_cast<const float4*>(gcol)[tid * 4 + q];
    float ov[4];
    const float tv[4] = {tq[q].x, tq[q].y, tq[q].z, tq[q].w};
    const float gv[4] = {gq.x, gq.y, gq.z, gq.w};
#pragma unroll
    for (int j = 0; j < 4; ++j) {
      unsigned u = __float_as_uint(tv[j]);
      bool keep;
      if (u == vstar) { keep = (exc < meq); ++exc; }
      else            { keep = (u > vstar); }
      ov[j] = (keep && u != 0u) ? gv[j] : 0.f;
    }
    reinterpret_cast<float4*>(ccol)[tid * 4 + q] =
        make_float4(ov[0], ov[1], ov[2], ov[3]);
  }
}

// ---------------------------------------------------------------------------
// Kernel 4: transpose combT[e][t] -> out[t][e]
// ---------------------------------------------------------------------------
__global__ __launch_bounds__(1024) void transpose_out(
    const float* __restrict__ combT, float* __restrict__ out1) {
  __shared__ float tile[64][65];
  const int tid  = (int)threadIdx.x;
  const int lane = tid & 63;
  const int wid  = tid >> 6;
  const int tok0 = (int)blockIdx.x * 64;
#pragma unroll
  for (int p = 0; p < 4; ++p) {
    const int e = p * 16 + wid;
    tile[lane][e] = combT[(size_t)e * N_TOK + tok0 + lane];
  }
  __syncthreads();
#pragma unroll
  for (int q = 0; q < 4; ++q) {
    const int tok = q * 16 + wid;
    out1[(size_t)(tok0 + tok) * NEXP + lane] = tile[tok][lane];
  }
}

// ---------------------------------------------------------------------------
// Kernel 5: aux loss  l_aux = sum_e (me_e/N * ce_e/N) * E
// ---------------------------------------------------------------------------
__global__ void aux_loss(const float* __restrict__ me_sum,
                         const int* __restrict__ ce_cnt,
                         float* __restrict__ out0) {
  const int lane = (int)threadIdx.x;
  float v = (me_sum[lane] / (float)N_TOK) *
            ((float)ce_cnt[lane] / (float)N_TOK);
#pragma unroll
  for (int off = 32; off > 0; off >>= 1) v += __shfl_xor(v, off);
  if (lane == 0) out0[0] = v * (float)NEXP;
}

// ---------------------------------------------------------------------------
extern "C" void kernel_launch(void* const* d_in, const int* in_sizes, int n_in,
                              void* d_out, int out_size, void* d_ws, size_t ws_size,
                              hipStream_t stream) {
  const float* x = (const float*)d_in[0];
  const float* W = (const float*)d_in[1];
  float* out = (float*)d_out;
  float* ws  = (float*)d_ws;

  // KS=8 needs (8+2)*4MB scratch; fall back to KS=4 if ws is smaller.
  const bool ks8 = ws_size >= (size_t)(8 + 2) * NE_TOT * 4 + 1024;
  const int  KS  = ks8 ? 8 : 4;

  float* part   = ws;                       // KS * 4 MB
  float* combT  = ws;                       // aliases part (dead by then)
  float* gatesT = ws + (size_t)KS * NE_TOT; // 4 MB
  float* tamT   = gatesT + NE_TOT;          // 4 MB
  float* me     = tamT + NE_TOT;
  int*   ce     = (int*)(me + 64);

  // W digit arrays (768 KB) live in the gatesT region: written by wdigits,
  // consumed by gemm_mfma, dead before gate_rows overwrites gatesT.
  unsigned short* Wh = (unsigned short*)gatesT;
  unsigned short* Wl = Wh + (size_t)NEXP * KDIM;
  unsigned short* Wq = Wl + (size_t)NEXP * KDIM;

  wdigits<<<(NEXP * KDIM) / 256, 256, 0, stream>>>(W, Wh, Wl, Wq);
  if (ks8) gemm_mfma<8><<<128 * 8, 256, 0, stream>>>(x, Wh, Wl, Wq, part);
  else     gemm_mfma<4><<<128 * 4, 256, 0, stream>>>(x, Wh, Wl, Wq, part);
  if (ks8) gate_rows<8><<<N_TOK / 64, 1024, 0, stream>>>(part, gatesT, tamT);
  else     gate_rows<4><<<N_TOK / 64, 1024, 0, stream>>>(part, gatesT, tamT);
  expert_select<<<NEXP, 1024, 0, stream>>>(gatesT, tamT, me, ce, combT);
  transpose_out<<<N_TOK / 64, 1024, 0, stream>>>(combT, out + 1);
  aux_loss<<<1, 64, 0, stream>>>(me, ce, out);
}

// Round 7
// 81.671 us; speedup vs baseline: 3.7810x; 1.0048x over previous
//
#include <hip/hip_runtime.h>
#include <cstdint>
#include <cstddef>

#define N_TOK  16384
#define NEXP   64
#define KDIM   2048
#define CAP    256   // ceil(16384/64 * 1.0) = 256
#define NE_TOT ((size_t)N_TOK * NEXP)

typedef __attribute__((ext_vector_type(8))) short short8;
typedef __attribute__((ext_vector_type(4))) float f32x4;

__device__ __forceinline__ unsigned short bf16_rtn(float f) {
  unsigned u = __float_as_uint(f);
  u += 0x7FFFu + ((u >> 16) & 1u);
  return (unsigned short)(u >> 16);
}
__device__ __forceinline__ float bf16_f(unsigned short h) {
  return __uint_as_float((unsigned)h << 16);
}
__device__ __forceinline__ f32x4 MF(short8 a, short8 b, f32x4 c) {
  return __builtin_amdgcn_mfma_f32_16x16x32_bf16(a, b, c, 0, 0, 0);
}

// ---------------------------------------------------------------------------
// Kernel 0: split W into 3 bf16 digits, packed [k/8][col][8] so a B-fragment
// (8 consecutive k of one col) is one aligned 16-B load.
// ---------------------------------------------------------------------------
__global__ __launch_bounds__(256) void wdigits(const float* __restrict__ W,
    unsigned short* __restrict__ Wh, unsigned short* __restrict__ Wl,
    unsigned short* __restrict__ Wq) {
  const int e = (int)blockIdx.x * 256 + (int)threadIdx.x;  // 0..131071
  const int col = e >> 11;
  const int k   = e & 2047;
  const float w = W[(size_t)col * KDIM + k];
  const unsigned short h = bf16_rtn(w);
  const float r1 = w - bf16_f(h);
  const unsigned short lo = bf16_rtn(r1);
  const float r2 = r1 - bf16_f(lo);
  const unsigned short q = bf16_rtn(r2);
  const size_t idx = (size_t)(k >> 3) * 512 + (size_t)col * 8 + (k & 7);
  Wh[idx] = h; Wl[idx] = lo; Wq[idx] = q;
}

// ---------------------------------------------------------------------------
// Kernel 1: logits via 6-term split-bf16 MFMA.
//   Wave = 32 rows x 64 cols; ks = bid/128 so a block's 4 waves SHARE the
//   B-fragment stream (L1-served). __launch_bounds__(256,4) pins 4 blocks/CU
//   (16 waves/CU) — register budget ~116: single A set (reloaded after digit
//   conversion), B-frags with 1-block lookahead (24 VGPR) instead of
//   12-resident (48).
// ---------------------------------------------------------------------------
__device__ __forceinline__ void cvt8(float4 a, float4 b,
                                     short8& h, short8& lo, short8& q) {
  float f[8] = {a.x, a.y, a.z, a.w, b.x, b.y, b.z, b.w};
#pragma unroll
  for (int j = 0; j < 8; ++j) {
    unsigned short hh = bf16_rtn(f[j]);
    float r1 = f[j] - bf16_f(hh);
    unsigned short ll = bf16_rtn(r1);
    float r2 = r1 - bf16_f(ll);
    h[j] = (short)hh; lo[j] = (short)ll; q[j] = (short)bf16_rtn(r2);
  }
}

template <int KS>
__global__ __launch_bounds__(256, 4) void gemm_mfma(const float* __restrict__ x,
    const unsigned short* __restrict__ Wh, const unsigned short* __restrict__ Wl,
    const unsigned short* __restrict__ Wq, float* __restrict__ part) {
  constexpr int NSTEP = (KDIM / KS) / 32;
  const int tid = (int)threadIdx.x;
  const int l   = tid & 63;
  const int wv  = tid >> 6;
  const int ks  = (int)blockIdx.x >> 7;          // 128 blocks per ks slice
  const int mt  = (((int)blockIdx.x & 127) << 2) + wv;  // 0..511
  const int row0 = mt * 32;
  const int kBeg = ks * (KDIM / KS);
  const int lr = l & 15;
  const int lk = l >> 4;

  f32x4 acc00 = {0.f,0.f,0.f,0.f}, acc01 = {0.f,0.f,0.f,0.f};
  f32x4 acc02 = {0.f,0.f,0.f,0.f}, acc03 = {0.f,0.f,0.f,0.f};
  f32x4 acc10 = {0.f,0.f,0.f,0.f}, acc11 = {0.f,0.f,0.f,0.f};
  f32x4 acc12 = {0.f,0.f,0.f,0.f}, acc13 = {0.f,0.f,0.f,0.f};

  const float* pa0 = x + (size_t)(row0 + lr) * KDIM + kBeg + lk * 8;
  const float* pa1 = pa0 + (size_t)16 * KDIM;
  const size_t bbase = ((size_t)((kBeg >> 3) + lk)) * 64 + lr;
  const short8* BH = (const short8*)Wh + bbase;
  const short8* BL = (const short8*)Wl + bbase;
  const short8* BQ = (const short8*)Wq + bbase;

  // initial A and first B block
  float4 A0a = *(const float4*)pa0;
  float4 A0b = *(const float4*)(pa0 + 4);
  float4 A1a = *(const float4*)pa1;
  float4 A1b = *(const float4*)(pa1 + 4);
  short8 bh = BH[0], bl = BL[0], bq = BQ[0];

  for (int s = 0; s < NSTEP; ++s) {
    const int so = s * 256;  // 4 col-blocks * 64 frags per 32-k step
    // digits from current A (A regs free after this)
    short8 a_h0, a_l0, a_q0, a_h1, a_l1, a_q1;
    cvt8(A0a, A0b, a_h0, a_l0, a_q0);
    cvt8(A1a, A1b, a_h1, a_l1, a_q1);
    // stream next A into the freed regs (hidden under 48 MFMAs + next cvt)
    if (s + 1 < NSTEP) {
      pa0 += 32; pa1 += 32;
      A0a = *(const float4*)pa0;
      A0b = *(const float4*)(pa0 + 4);
      A1a = *(const float4*)pa1;
      A1b = *(const float4*)(pa1 + 4);
    }

#define CT_BLOCK(ACC0, ACC1)                                         \
    ACC0 = MF(a_h0, bh, ACC0); ACC0 = MF(a_h0, bl, ACC0);            \
    ACC0 = MF(a_l0, bh, ACC0); ACC0 = MF(a_l0, bl, ACC0);            \
    ACC0 = MF(a_q0, bh, ACC0); ACC0 = MF(a_h0, bq, ACC0);            \
    ACC1 = MF(a_h1, bh, ACC1); ACC1 = MF(a_h1, bl, ACC1);            \
    ACC1 = MF(a_l1, bh, ACC1); ACC1 = MF(a_l1, bl, ACC1);            \
    ACC1 = MF(a_q1, bh, ACC1); ACC1 = MF(a_h1, bq, ACC1);

    // col-block 0 (prefetch 1)
    short8 nh = BH[so + 16], nl = BL[so + 16], nq = BQ[so + 16];
    CT_BLOCK(acc00, acc10)
    bh = nh; bl = nl; bq = nq;
    // col-block 1 (prefetch 2)
    nh = BH[so + 32]; nl = BL[so + 32]; nq = BQ[so + 32];
    CT_BLOCK(acc01, acc11)
    bh = nh; bl = nl; bq = nq;
    // col-block 2 (prefetch 3)
    nh = BH[so + 48]; nl = BL[so + 48]; nq = BQ[so + 48];
    CT_BLOCK(acc02, acc12)
    bh = nh; bl = nl; bq = nq;
    // col-block 3 (prefetch next step's block 0)
    const int ni = (s + 1 < NSTEP) ? so + 256 : so;
    nh = BH[ni]; nl = BL[ni]; nq = BQ[ni];
    CT_BLOCK(acc03, acc13)
    bh = nh; bl = nl; bq = nq;
#undef CT_BLOCK
  }

  float* pout = part + (size_t)ks * NE_TOT;
  const int rb = row0 + lk * 4;
#pragma unroll
  for (int r = 0; r < 4; ++r) {
    pout[(size_t)(rb + r) * 64 +  0 + lr] = acc00[r];
    pout[(size_t)(rb + r) * 64 + 16 + lr] = acc01[r];
    pout[(size_t)(rb + r) * 64 + 32 + lr] = acc02[r];
    pout[(size_t)(rb + r) * 64 + 48 + lr] = acc03[r];
    pout[(size_t)(rb + 16 + r) * 64 +  0 + lr] = acc10[r];
    pout[(size_t)(rb + 16 + r) * 64 + 16 + lr] = acc11[r];
    pout[(size_t)(rb + 16 + r) * 64 + 32 + lr] = acc12[r];
    pout[(size_t)(rb + 16 + r) * 64 + 48 + lr] = acc13[r];
  }
}

// ---------------------------------------------------------------------------
// Kernel 2: per-row gating -> TRANSPOSED outputs gatesT[e][t], tamT[e][t].
//   (unchanged — verified)
// ---------------------------------------------------------------------------
template <int KS>
__global__ __launch_bounds__(1024) void gate_rows(const float* __restrict__ part,
                                                  float* __restrict__ gatesT,
                                                  float* __restrict__ tamT) {
  __shared__ float gt[64][65];
  __shared__ float tt[64][65];
  const int tid  = (int)threadIdx.x;
  const int lane = tid & 63;
  const int wid  = tid >> 6;
  const int row0 = (int)blockIdx.x * 64;

#pragma unroll
  for (int r = 0; r < 4; ++r) {
    const int rloc = wid * 4 + r;
    const size_t base = (size_t)(row0 + rloc) * NEXP;

    float logit = 0.f;
#pragma unroll
    for (int s = 0; s < KS; ++s)
      logit += part[(size_t)s * NE_TOT + base + lane];

    float m = logit;
#pragma unroll
    for (int off = 32; off > 0; off >>= 1) m = fmaxf(m, __shfl_xor(m, off));
    float p = expf(logit - m);
    float sum = p;
#pragma unroll
    for (int off = 32; off > 0; off >>= 1) sum += __shfl_xor(sum, off);
    const float gate = p / sum;

    float g = gate;
    int idx = lane;
#pragma unroll
    for (int k = 2; k <= 64; k <<= 1) {
#pragma unroll
      for (int j = k >> 1; j > 0; j >>= 1) {
        float og = __shfl_xor(g, j);
        int   oi = __shfl_xor(idx, j);
        bool iLower     = (lane & j) == 0;
        bool wantFirst  = ((lane & k) == 0) ? iLower : !iLower;
        bool otherFirst = (og > g) || (og == g && oi < idx);
        if (otherFirst == wantFirst) { g = og; idx = oi; }
      }
    }

    float cum = g;
#pragma unroll
    for (int off = 1; off < 64; off <<= 1) {
      float t = __shfl_up(cum, off);
      if (lane >= off) cum += t;
    }
    const bool chosen = (lane == 0) || ((cum - g) < 0.5f);
    const float imp = chosen ? ((float)(NEXP - lane) + g) : 0.f;

    gt[rloc][lane] = gate;
    tt[rloc][idx]  = imp;
  }
  __syncthreads();

#pragma unroll
  for (int p = 0; p < 4; ++p) {
    const int e = p * 16 + wid;
    gatesT[(size_t)e * N_TOK + row0 + lane] = gt[lane][e];
    tamT  [(size_t)e * N_TOK + row0 + lane] = tt[lane][e];
  }
}

// ---------------------------------------------------------------------------
// Kernel 3: per-expert capacity truncation (unchanged — verified)
// ---------------------------------------------------------------------------
__global__ __launch_bounds__(1024) void expert_select(
    const float* __restrict__ gatesT, const float* __restrict__ tamT,
    float* __restrict__ me_sum, int* __restrict__ ce_cnt,
    float* __restrict__ combT) {
  __shared__ int   hist16[16][256];
  __shared__ int   hist[256];
  __shared__ float wsum[16];
  __shared__ int   wice[16];
  __shared__ int   wnnz[16];
  __shared__ int   wcnt[16];
  __shared__ unsigned sh_prefix;
  __shared__ int      sh_k;
  __shared__ int      sh_nnz;

  const int e    = (int)blockIdx.x;
  const int tid  = (int)threadIdx.x;
  const int lane = tid & 63;
  const int wid  = tid >> 6;
  const float* tcol = tamT   + (size_t)e * N_TOK;
  const float* gcol = gatesT + (size_t)e * N_TOK;

  float gsum = 0.f;
  int ccnt = 0, nnzl = 0;
#pragma unroll
  for (int k = 0; k < 4; ++k) {
    int i4 = tid + k * 1024;
    float4 tv = reinterpret_cast<const float4*>(tcol)[i4];
    float4 gv = reinterpret_cast<const float4*>(gcol)[i4];
    gsum += gv.x + gv.y + gv.z + gv.w;
    ccnt += (tv.x > 64.f) + (tv.y > 64.f) + (tv.z > 64.f) + (tv.w > 64.f);
    nnzl += (tv.x != 0.f) + (tv.y != 0.f) + (tv.z != 0.f) + (tv.w != 0.f);
  }
#pragma unroll
  for (int off = 32; off > 0; off >>= 1) {
    gsum += __shfl_xor(gsum, off);
    ccnt += __shfl_xor(ccnt, off);
    nnzl += __shfl_xor(nnzl, off);
  }
  if (lane == 0) { wsum[wid] = gsum; wice[wid] = ccnt; wnnz[wid] = nnzl; }
  __syncthreads();
  if (tid == 0) {
    float t = 0.f; int c = 0, nz = 0;
    for (int w = 0; w < 16; ++w) { t += wsum[w]; c += wice[w]; nz += wnnz[w]; }
    me_sum[e] = t; ce_cnt[e] = c; sh_nnz = nz;
  }
  __syncthreads();
  const int nnz = sh_nnz;

  unsigned vstar = 0u;
  int meq = 0;
  if (nnz > CAP) {
    unsigned prefix = 0;
    int krem = CAP;
    for (int round = 0; round < 4; ++round) {
      const int shift = 24 - 8 * round;
      const unsigned maskAbove =
          (round == 0) ? 0u : (0xFFFFFFFFu << (shift + 8));
      for (int z = tid; z < 16 * 256; z += 1024) ((int*)hist16)[z] = 0;
      __syncthreads();
#pragma unroll
      for (int k = 0; k < 16; ++k) {
        unsigned u = __float_as_uint(tcol[tid + k * 1024]);
        if (u != 0u && (u & maskAbove) == prefix)
          atomicAdd(&hist16[wid][(u >> shift) & 255], 1);
      }
      __syncthreads();
      if (tid < 256) {
        int s = 0;
#pragma unroll
        for (int w = 0; w < 16; ++w) s += hist16[w][tid];
        hist[tid] = s;
      }
      __syncthreads();
      if (wid == 0) {
        int h0 = hist[lane * 4 + 0], h1 = hist[lane * 4 + 1];
        int h2 = hist[lane * 4 + 2], h3 = hist[lane * 4 + 3];
        int lsum = h0 + h1 + h2 + h3;
        int suf = lsum;
#pragma unroll
        for (int off = 1; off < 64; off <<= 1) {
          int t = __shfl_down(suf, off);
          if (lane + off < 64) suf += t;
        }
        int above = suf - lsum;
        int S3 = above + h3, S2 = S3 + h2, S1 = S2 + h1, S0 = S1 + h0;
        if (S0 >= krem && S1    < krem) { sh_prefix = prefix | ((unsigned)(lane*4+0) << shift); sh_k = krem - S1;    }
        if (S1 >= krem && S2    < krem) { sh_prefix = prefix | ((unsigned)(lane*4+1) << shift); sh_k = krem - S2;    }
        if (S2 >= krem && S3    < krem) { sh_prefix = prefix | ((unsigned)(lane*4+2) << shift); sh_k = krem - S3;    }
        if (S3 >= krem && above < krem) { sh_prefix = prefix | ((unsigned)(lane*4+3) << shift); sh_k = krem - above; }
      }
      __syncthreads();
      prefix = sh_prefix;
      krem   = sh_k;
      __syncthreads();
    }
    vstar = prefix;
    meq   = krem;
  }

  float4 tq[4];
#pragma unroll
  for (int q = 0; q < 4; ++q)
    tq[q] = reinterpret_cast<const float4*>(tcol)[tid * 4 + q];
  int cnt = 0;
#pragma unroll
  for (int q = 0; q < 4; ++q) {
    cnt += (__float_as_uint(tq[q].x) == vstar);
    cnt += (__float_as_uint(tq[q].y) == vstar);
    cnt += (__float_as_uint(tq[q].z) == vstar);
    cnt += (__float_as_uint(tq[q].w) == vstar);
  }
  int inc = cnt;
#pragma unroll
  for (int off = 1; off < 64; off <<= 1) {
    int t = __shfl_up(inc, off);
    if (lane >= off) inc += t;
  }
  if (lane == 63) wcnt[wid] = inc;
  __syncthreads();
  if (tid == 0) {
    int run = 0;
    for (int w = 0; w < 16; ++w) { int t = wcnt[w]; wcnt[w] = run; run += t; }
  }
  __syncthreads();
  int exc = (inc - cnt) + wcnt[wid];

  float* ccol = combT + (size_t)e * N_TOK;
#pragma unroll
  for (int q = 0; q < 4; ++q) {
    float4 gq = reinterpret_cast<const float4*>(gcol)[tid * 4 + q];
    float ov[4];
    const float tv[4] = {tq[q].x, tq[q].y, tq[q].z, tq[q].w};
    const float gv[4] = {gq.x, gq.y, gq.z, gq.w};
#pragma unroll
    for (int j = 0; j < 4; ++j) {
      unsigned u = __float_as_uint(tv[j]);
      bool keep;
      if (u == vstar) { keep = (exc < meq); ++exc; }
      else            { keep = (u > vstar); }
      ov[j] = (keep && u != 0u) ? gv[j] : 0.f;
    }
    reinterpret_cast<float4*>(ccol)[tid * 4 + q] =
        make_float4(ov[0], ov[1], ov[2], ov[3]);
  }
}

// ---------------------------------------------------------------------------
// Kernel 4: transpose combT[e][t] -> out[t][e]; block 0 also computes l_aux
// (me/ce written by the preceding expert_select — stream-ordered).
// ---------------------------------------------------------------------------
__global__ __launch_bounds__(1024) void transpose_out(
    const float* __restrict__ combT, float* __restrict__ out1,
    const float* __restrict__ me_sum, const int* __restrict__ ce_cnt,
    float* __restrict__ out0) {
  __shared__ float tile[64][65];
  const int tid  = (int)threadIdx.x;
  const int lane = tid & 63;
  const int wid  = tid >> 6;
  const int tok0 = (int)blockIdx.x * 64;
#pragma unroll
  for (int p = 0; p < 4; ++p) {
    const int e = p * 16 + wid;
    tile[lane][e] = combT[(size_t)e * N_TOK + tok0 + lane];
  }
  __syncthreads();
#pragma unroll
  for (int q = 0; q < 4; ++q) {
    const int tok = q * 16 + wid;
    out1[(size_t)(tok0 + tok) * NEXP + lane] = tile[tok][lane];
  }
  if (blockIdx.x == 0 && wid == 0) {
    float v = (me_sum[lane] / (float)N_TOK) *
              ((float)ce_cnt[lane] / (float)N_TOK);
#pragma unroll
    for (int off = 32; off > 0; off >>= 1) v += __shfl_xor(v, off);
    if (lane == 0) out0[0] = v * (float)NEXP;
  }
}

// ---------------------------------------------------------------------------
extern "C" void kernel_launch(void* const* d_in, const int* in_sizes, int n_in,
                              void* d_out, int out_size, void* d_ws, size_t ws_size,
                              hipStream_t stream) {
  const float* x = (const float*)d_in[0];
  const float* W = (const float*)d_in[1];
  float* out = (float*)d_out;
  float* ws  = (float*)d_ws;

  // KS=8 needs (8+2)*4MB scratch; fall back to KS=4 if ws is smaller.
  const bool ks8 = ws_size >= (size_t)(8 + 2) * NE_TOT * 4 + 1024;
  const int  KS  = ks8 ? 8 : 4;

  float* part   = ws;                       // KS * 4 MB
  float* combT  = ws;                       // aliases part (dead by then)
  float* gatesT = ws + (size_t)KS * NE_TOT; // 4 MB
  float* tamT   = gatesT + NE_TOT;          // 4 MB
  float* me     = tamT + NE_TOT;
  int*   ce     = (int*)(me + 64);

  // W digit arrays (768 KB) live in the gatesT region: written by wdigits,
  // consumed by gemm_mfma, dead before gate_rows overwrites gatesT.
  unsigned short* Wh = (unsigned short*)gatesT;
  unsigned short* Wl = Wh + (size_t)NEXP * KDIM;
  unsigned short* Wq = Wl + (size_t)NEXP * KDIM;

  wdigits<<<(NEXP * KDIM) / 256, 256, 0, stream>>>(W, Wh, Wl, Wq);
  if (ks8) gemm_mfma<8><<<128 * 8, 256, 0, stream>>>(x, Wh, Wl, Wq, part);
  else     gemm_mfma<4><<<128 * 4, 256, 0, stream>>>(x, Wh, Wl, Wq, part);
  if (ks8) gate_rows<8><<<N_TOK / 64, 1024, 0, stream>>>(part, gatesT, tamT);
  else     gate_rows<4><<<N_TOK / 64, 1024, 0, stream>>>(part, gatesT, tamT);
  expert_select<<<NEXP, 1024, 0, stream>>>(gatesT, tamT, me, ce, combT);
  transpose_out<<<N_TOK / 64, 1024, 0, stream>>>(combT, out + 1, me, ce, out);
}